// Round 18
// baseline (611.842 us; speedup 1.0000x reference)
//
#include <hip/hip_runtime.h>
#include <hip/hip_fp16.h>
#include <math.h>
#include <stdint.h>

#define NN 50000
#define NE 800000
#define ET (NE + NN)      // 850000 edges incl self loops
#define FIN 128
#define DD 250
#define HD 256
#define NQ 200000
#define NEG_SLOPE 0.2f

typedef unsigned short u16;
typedef __attribute__((ext_vector_type(8))) short bf16x8;
typedef __attribute__((ext_vector_type(4))) float f32x4;
typedef _Float16 h2v __attribute__((ext_vector_type(2)));

__device__ __forceinline__ u16 f2bf_rne(float x) {
    unsigned int b = __float_as_uint(x);
    unsigned int r = (b + 0x7FFFu + ((b >> 16) & 1u)) >> 16;
    return (u16)r;
}
__device__ __forceinline__ void split2(float v, u16& h, u16& l) {
    unsigned int b = __float_as_uint(v);
    h = (u16)(b >> 16);
    float r = v - __uint_as_float(b & 0xFFFF0000u);
    l = f2bf_rne(r);
}
__device__ __forceinline__ u16 f2h(float v) {
    __half h = __float2half(v);
    return *reinterpret_cast<u16*>(&h);
}
// load 4 fp16 (8B) -> float4 (used by query kernel)
__device__ __forceinline__ float4 ld4h(const u16* p) {
    uint2 r = *(const uint2*)p;
    __half2 a = *(__half2*)&r.x;
    __half2 b = *(__half2*)&r.y;
    float2 fa = __half22float2(a), fb = __half22float2(b);
    return make_float4(fa.x, fa.y, fb.x, fb.y);
}
// packed fp16 max -> v_pk_max_f16 (avoids ROCm __hmax2 header overload issues)
__device__ __forceinline__ h2v hmax2v(h2v a, h2v b) {
    return __builtin_elementwise_max(a, b);
}

// ---------------- CSR build ----------------

__global__ void count_kernel(const int* __restrict__ ei, int* __restrict__ cnt) {
    int k = blockIdx.x * 256 + threadIdx.x;
    if (k >= ET) return;
    int d = (k < NE) ? ei[NE + k] : (k - NE);
    atomicAdd(&cnt[d], 1);
}

__global__ __launch_bounds__(256) void scan1_kernel(
    int* __restrict__ cnt, int* __restrict__ rowptr, int* __restrict__ bsum)
{
    __shared__ int buf[256];
    int t = threadIdx.x;
    int i = blockIdx.x * 256 + t;
    int v = (i < NN) ? cnt[i] : 0;
    if (i < NN) cnt[i] = 0;          // zero fill for scatter
    buf[t] = v;
    __syncthreads();
#pragma unroll
    for (int off = 1; off < 256; off <<= 1) {
        int add = (t >= off) ? buf[t - off] : 0;
        __syncthreads();
        buf[t] += add;
        __syncthreads();
    }
    if (i < NN) rowptr[i] = buf[t] - v;     // block-local exclusive
    if (t == 255) bsum[blockIdx.x] = buf[255];
}

__global__ __launch_bounds__(256) void scan2_kernel(
    int* __restrict__ bsum, int* __restrict__ rowptr, int nb)
{
    __shared__ int buf[256];
    int t = threadIdx.x;
    int v = (t < nb) ? bsum[t] : 0;
    buf[t] = v;
    __syncthreads();
#pragma unroll
    for (int off = 1; off < 256; off <<= 1) {
        int add = (t >= off) ? buf[t - off] : 0;
        __syncthreads();
        buf[t] += add;
        __syncthreads();
    }
    if (t < nb) bsum[t] = buf[t] - v;
    if (t == 255) rowptr[NN] = buf[255];
}

__global__ __launch_bounds__(256) void scan3_kernel(
    int* __restrict__ rowptr, const int* __restrict__ bsum)
{
    int i = blockIdx.x * 256 + threadIdx.x;
    if (i < NN) rowptr[i] += bsum[blockIdx.x];
}

// stores premultiplied src BYTE offset (s*512, fp16-row stride) for the fused kernel
__global__ void scatter_kernel(const int* __restrict__ ei,
                               const int* __restrict__ rowptr,
                               int* __restrict__ fill,
                               int* __restrict__ ssrc) {
    int k = blockIdx.x * 256 + threadIdx.x;
    if (k >= ET) return;
    int s, d;
    if (k < NE) { s = ei[k]; d = ei[NE + k]; }
    else        { s = k - NE; d = k - NE; }
    int pos = rowptr[d] + atomicAdd(&fill[d], 1);
    ssrc[pos] = s << 9;
}

// ---------------- combined conversion kernel ----------------

#define CONVX_BLOCKS 3125

__global__ __launch_bounds__(256) void conv_all(
    const float* __restrict__ x, int* __restrict__ fill,
    u16* __restrict__ Ah, u16* __restrict__ Al,
    const float* __restrict__ W1l, const float* __restrict__ W1r,
    const float* __restrict__ W2l, const float* __restrict__ W2r,
    const float* __restrict__ Wm1,
    u16* __restrict__ W1lTh, u16* __restrict__ W1lTl,
    u16* __restrict__ W1rTh, u16* __restrict__ W1rTl,
    u16* __restrict__ W2lTh, u16* __restrict__ W2lTl,
    u16* __restrict__ W2rTh, u16* __restrict__ W2rTl,
    u16* __restrict__ WmtTh, u16* __restrict__ WmtTl,
    u16* __restrict__ WmbTh, u16* __restrict__ WmbTl)
{
    if (blockIdx.x < CONVX_BLOCKS) {
        int tid = blockIdx.x * 256 + threadIdx.x;
        if (tid < NN) fill[tid] = 0;
        size_t idx = (size_t)tid * 8;
        if (idx >= (size_t)NN * FIN) return;
        float4 v0 = *(const float4*)(x + idx);
        float4 v1 = *(const float4*)(x + idx + 4);
        float vv[8] = {v0.x, v0.y, v0.z, v0.w, v1.x, v1.y, v1.z, v1.w};
        bf16x8 h, l;
#pragma unroll
        for (int j = 0; j < 8; j++) {
            u16 hh, ll;
            split2(vv[j], hh, ll);
            h[j] = (short)hh; l[j] = (short)ll;
        }
        *(bf16x8*)(Ah + idx) = h;
        *(bf16x8*)(Al + idx) = l;
        return;
    }
    int b = blockIdx.x - CONVX_BLOCKS;
    const float* W; int K, N, koff, kshift, b0; u16 *oh, *ol;
    if (b < 128)       { W = W1l; K = FIN; N = DD; koff = 0;  kshift = 7; b0 = 0;    oh = W1lTh; ol = W1lTl; }
    else if (b < 256)  { W = W1r; K = FIN; N = DD; koff = 0;  kshift = 7; b0 = 128;  oh = W1rTh; ol = W1rTl; }
    else if (b < 512)  { W = W2l; K = DD;  N = DD; koff = 0;  kshift = 8; b0 = 256;  oh = W2lTh; ol = W2lTl; }
    else if (b < 768)  { W = W2r; K = DD;  N = DD; koff = 0;  kshift = 8; b0 = 512;  oh = W2rTh; ol = W2rTl; }
    else if (b < 1024) { W = Wm1; K = DD;  N = HD; koff = 0;  kshift = 8; b0 = 768;  oh = WmtTh; ol = WmtTl; }
    else               { W = Wm1; K = DD;  N = HD; koff = DD; kshift = 8; b0 = 1024; oh = WmbTh; ol = WmbTl; }
    int id = (b - b0) * 256 + threadIdx.x;
    int Kp = 1 << kshift;
    int n = id >> kshift, k = id & (Kp - 1);
    float v = (n < N && k < K) ? W[(size_t)(k + koff) * N + n] : 0.f;
    u16 h, l;
    split2(v, h, l);
    oh[id] = h;
    ol[id] = l;
}

// ---------------- pre-split bf16 MFMA GEMM (one output per block) ----------------
// blockIdx.z selects which of the pair (C0/C1) this block computes -> 2x blocks,
// half the LDS (41KB -> 3 blocks/CU), half per-iter MFMA burst. A+B staged in LDS
// (B-direct-global measured 36% slower in R15 - 512B-strided fragment loads).
// fmt bit z: output as fp16 stride-256; else fp32 stride-N.

#define AP 40   // padded LDS row length (u16)

__global__ __launch_bounds__(256, 3) void gemm_pair(
    const u16* __restrict__ Ah, const u16* __restrict__ Al, int Kp,
    const u16* __restrict__ B0h, const u16* __restrict__ B0l,
    const u16* __restrict__ B1h, const u16* __restrict__ B1l,
    const float* __restrict__ bias0, const float* __restrict__ bias1,
    void* __restrict__ C0v, void* __restrict__ C1v, int M, int N, int fmt)
{
    __shared__ u16 AhS[128][AP], AlS[128][AP];
    __shared__ u16 BhS[128][AP], BlS[128][AP];

    int z = blockIdx.z;
    const u16* Bh = z ? B1h : B0h;
    const u16* Bl = z ? B1l : B0l;
    const float* bias = z ? bias1 : bias0;
    void* Cv = z ? C1v : C0v;
    int cfmt = (fmt >> z) & 1;

    int row0 = blockIdx.x * 128;
    int col0 = blockIdx.y * 128;
    int t = threadIdx.x;
    int lane = t & 63, w = t >> 6;
    int wr = w >> 1, wc = w & 1;
    int quad = lane >> 4, rr = lane & 15;

    f32x4 acc[4][4];
#pragma unroll
    for (int i = 0; i < 4; i++)
#pragma unroll
        for (int j = 0; j < 4; j++)
            acc[i][j] = (f32x4){0.f, 0.f, 0.f, 0.f};

    int ar = t >> 1, akh = (t & 1) * 16;
    int gr = row0 + ar;
    int nB = col0 + ar;
    const u16* pAh = Ah + (size_t)gr * Kp + akh;
    const u16* pAl = Al + (size_t)gr * Kp + akh;
    const u16* pBh = Bh + (size_t)nB * Kp + akh;
    const u16* pBl = Bl + (size_t)nB * Kp + akh;

    for (int k0 = 0; k0 < Kp; k0 += 32) {
        bf16x8 ah0{}, ah1{}, al0{}, al1{};
        if (gr < M) {
            ah0 = *(const bf16x8*)(pAh + k0);
            ah1 = *(const bf16x8*)(pAh + k0 + 8);
            al0 = *(const bf16x8*)(pAl + k0);
            al1 = *(const bf16x8*)(pAl + k0 + 8);
        }
        *(bf16x8*)&AhS[ar][akh]     = ah0;
        *(bf16x8*)&AhS[ar][akh + 8] = ah1;
        *(bf16x8*)&AlS[ar][akh]     = al0;
        *(bf16x8*)&AlS[ar][akh + 8] = al1;
        *(bf16x8*)&BhS[ar][akh]     = *(const bf16x8*)(pBh + k0);
        *(bf16x8*)&BhS[ar][akh + 8] = *(const bf16x8*)(pBh + k0 + 8);
        *(bf16x8*)&BlS[ar][akh]     = *(const bf16x8*)(pBl + k0);
        *(bf16x8*)&BlS[ar][akh + 8] = *(const bf16x8*)(pBl + k0 + 8);
        __syncthreads();

        bf16x8 fAh[4], fAl[4];
#pragma unroll
        for (int fi = 0; fi < 4; fi++) {
            int r = wr * 64 + fi * 16 + rr;
            fAh[fi] = *(const bf16x8*)&AhS[r][quad * 8];
            fAl[fi] = *(const bf16x8*)&AlS[r][quad * 8];
        }
#pragma unroll
        for (int fj = 0; fj < 4; fj++) {
            int c = wc * 64 + fj * 16 + rr;
            bf16x8 bh = *(const bf16x8*)&BhS[c][quad * 8];
            bf16x8 bl = *(const bf16x8*)&BlS[c][quad * 8];
#pragma unroll
            for (int fi = 0; fi < 4; fi++) {
                acc[fi][fj] = __builtin_amdgcn_mfma_f32_16x16x32_bf16(fAh[fi], bh, acc[fi][fj], 0, 0, 0);
                acc[fi][fj] = __builtin_amdgcn_mfma_f32_16x16x32_bf16(fAh[fi], bl, acc[fi][fj], 0, 0, 0);
                acc[fi][fj] = __builtin_amdgcn_mfma_f32_16x16x32_bf16(fAl[fi], bh, acc[fi][fj], 0, 0, 0);
            }
        }
        __syncthreads();
    }

#pragma unroll
    for (int fj = 0; fj < 4; fj++) {
        int gc = col0 + wc * 64 + fj * 16 + rr;
        if (gc >= N) continue;
        float bb = bias ? bias[gc] : 0.f;
#pragma unroll
        for (int fi = 0; fi < 4; fi++) {
#pragma unroll
            for (int r = 0; r < 4; r++) {
                int grr = row0 + wr * 64 + fi * 16 + quad * 4 + r;
                if (grr < M) {
                    float v = acc[fi][fj][r] + bb;
                    if (cfmt) ((u16*)Cv)[(size_t)grr * 256 + gc] = f2h(v);
                    else      ((float*)Cv)[(size_t)grr * N + gc] = v;
                }
            }
        }
    }
}

// ---------------- fused edge phase: packed-fp16 single-pass softmax+aggregate ----------------
// 4-edge unroll full-wave. Wave-uniform scalarization: beg/end/ssrc offsets go through
// readfirstlane so edge offsets live in SGPRs (s_load + saddr addressing, ~0 VALU/load).

__global__ __launch_bounds__(256) void fused_edge_kernel(
    const int* __restrict__ rowptr, const int* __restrict__ ssrc,
    const u16* __restrict__ xl16, const float* __restrict__ xr,
    const float* __restrict__ att,
    u16* __restrict__ Oh, u16* __restrict__ Ol, int dorelu)
{
    int i = blockIdx.x * 4 + (threadIdx.x >> 6);
    if (i >= NN) return;
    int lane = threadIdx.x & 63;
    int beg = __builtin_amdgcn_readfirstlane(rowptr[i]);
    int end = __builtin_amdgcn_readfirstlane(rowptr[i + 1]);
    int d0 = lane * 4;
    int lb = d0 * 2;                 // lane byte offset into fp16 row

    // masked fp32 loads of xr/att for this lane's 4 dims, converted to fp16 pairs
    float xrf[4] = {0.f, 0.f, 0.f, 0.f};
    float atf[4] = {0.f, 0.f, 0.f, 0.f};
#pragma unroll
    for (int j = 0; j < 4; j++) {
        if (d0 + j < DD) {
            xrf[j] = xr[(size_t)i * DD + d0 + j];
            atf[j] = att[d0 + j];
        }
    }
    h2v xr0h, xr1h, at0h, at1h;
    xr0h.x = (_Float16)xrf[0]; xr0h.y = (_Float16)xrf[1];
    xr1h.x = (_Float16)xrf[2]; xr1h.y = (_Float16)xrf[3];
    at0h.x = (_Float16)atf[0]; at0h.y = (_Float16)atf[1];
    at1h.x = (_Float16)atf[2]; at1h.y = (_Float16)atf[3];
    const h2v c02 = {(_Float16)0.2f, (_Float16)0.2f};

    const char* xlb = (const char*)xl16;

    float m = -1e30f, ssum = 0.f;
    float4 acc = make_float4(0.f, 0.f, 0.f, 0.f);

    int p = beg;
    for (; p + 3 < end; p += 4) {
        int o0 = __builtin_amdgcn_readfirstlane(ssrc[p]);
        int o1 = __builtin_amdgcn_readfirstlane(ssrc[p + 1]);
        int o2 = __builtin_amdgcn_readfirstlane(ssrc[p + 2]);
        int o3 = __builtin_amdgcn_readfirstlane(ssrc[p + 3]);
        uint2 r0 = *(const uint2*)(xlb + o0 + lb);
        uint2 r1 = *(const uint2*)(xlb + o1 + lb);
        uint2 r2 = *(const uint2*)(xlb + o2 + lb);
        uint2 r3 = *(const uint2*)(xlb + o3 + lb);
        h2v x00 = *(h2v*)&r0.x, x01 = *(h2v*)&r0.y;
        h2v x10 = *(h2v*)&r1.x, x11 = *(h2v*)&r1.y;
        h2v x20 = *(h2v*)&r2.x, x21 = *(h2v*)&r2.y;
        h2v x30 = *(h2v*)&r3.x, x31 = *(h2v*)&r3.y;

        h2v s;
        float e0, e1, e2, e3;
        s = x00 + xr0h; s = hmax2v(s, s * c02);
        e0 = __builtin_amdgcn_fdot2(s, at0h, 0.f, false);
        s = x01 + xr1h; s = hmax2v(s, s * c02);
        e0 = __builtin_amdgcn_fdot2(s, at1h, e0, false);
        s = x10 + xr0h; s = hmax2v(s, s * c02);
        e1 = __builtin_amdgcn_fdot2(s, at0h, 0.f, false);
        s = x11 + xr1h; s = hmax2v(s, s * c02);
        e1 = __builtin_amdgcn_fdot2(s, at1h, e1, false);
        s = x20 + xr0h; s = hmax2v(s, s * c02);
        e2 = __builtin_amdgcn_fdot2(s, at0h, 0.f, false);
        s = x21 + xr1h; s = hmax2v(s, s * c02);
        e2 = __builtin_amdgcn_fdot2(s, at1h, e2, false);
        s = x30 + xr0h; s = hmax2v(s, s * c02);
        e3 = __builtin_amdgcn_fdot2(s, at0h, 0.f, false);
        s = x31 + xr1h; s = hmax2v(s, s * c02);
        e3 = __builtin_amdgcn_fdot2(s, at1h, e3, false);

#pragma unroll
        for (int off = 1; off < 64; off <<= 1) {
            e0 += __shfl_xor(e0, off, 64);
            e1 += __shfl_xor(e1, off, 64);
            e2 += __shfl_xor(e2, off, 64);
            e3 += __shfl_xor(e3, off, 64);
        }
        float nm = fmaxf(fmaxf(m, e0), fmaxf(fmaxf(e1, e2), e3));
        float sc = __expf(m - nm);
        float w0 = __expf(e0 - nm);
        float w1 = __expf(e1 - nm);
        float w2 = __expf(e2 - nm);
        float w3 = __expf(e3 - nm);
        // tree-paired accumulate (short dep chains; fma_mix folds the h->f cvt)
        float ax0 = fmaf(w1, (float)x10.x, w0 * (float)x00.x);
        float ax1 = fmaf(w3, (float)x30.x, w2 * (float)x20.x);
        float ay0 = fmaf(w1, (float)x10.y, w0 * (float)x00.y);
        float ay1 = fmaf(w3, (float)x30.y, w2 * (float)x20.y);
        float az0 = fmaf(w1, (float)x11.x, w0 * (float)x01.x);
        float az1 = fmaf(w3, (float)x31.x, w2 * (float)x21.x);
        float aw0 = fmaf(w1, (float)x11.y, w0 * (float)x01.y);
        float aw1 = fmaf(w3, (float)x31.y, w2 * (float)x21.y);
        acc.x = fmaf(acc.x, sc, ax0 + ax1);
        acc.y = fmaf(acc.y, sc, ay0 + ay1);
        acc.z = fmaf(acc.z, sc, az0 + az1);
        acc.w = fmaf(acc.w, sc, aw0 + aw1);
        ssum = fmaf(ssum, sc, (w0 + w1) + (w2 + w3));
        m = nm;
    }
    for (; p < end; p++) {
        int o = __builtin_amdgcn_readfirstlane(ssrc[p]);
        uint2 r = *(const uint2*)(xlb + o + lb);
        h2v x0 = *(h2v*)&r.x, x1 = *(h2v*)&r.y;
        h2v s;
        float e;
        s = x0 + xr0h; s = hmax2v(s, s * c02);
        e = __builtin_amdgcn_fdot2(s, at0h, 0.f, false);
        s = x1 + xr1h; s = hmax2v(s, s * c02);
        e = __builtin_amdgcn_fdot2(s, at1h, e, false);
#pragma unroll
        for (int off = 1; off < 64; off <<= 1)
            e += __shfl_xor(e, off, 64);
        float nm = fmaxf(m, e);
        float sc = __expf(m - nm);
        float w = __expf(e - nm);
        acc.x = fmaf(w, (float)x0.x, acc.x * sc);
        acc.y = fmaf(w, (float)x0.y, acc.y * sc);
        acc.z = fmaf(w, (float)x1.x, acc.z * sc);
        acc.w = fmaf(w, (float)x1.y, acc.w * sc);
        ssum = fmaf(ssum, sc, w);
        m = nm;
    }

    float inv = 1.f / ssum;
    acc.x *= inv; acc.y *= inv; acc.z *= inv; acc.w *= inv;
    if (dorelu) {
        acc.x = fmaxf(acc.x, 0.f); acc.y = fmaxf(acc.y, 0.f);
        acc.z = fmaxf(acc.z, 0.f); acc.w = fmaxf(acc.w, 0.f);
    }
    size_t base = (size_t)i * 256 + d0;
    u16 hx, lx, hy, ly, hz, lz, hw, lw;
    split2(acc.x, hx, lx); split2(acc.y, hy, ly);
    split2(acc.z, hz, lz); split2(acc.w, hw, lw);
    ushort4 hv; hv.x = hx; hv.y = hy; hv.z = hz; hv.w = hw;
    ushort4 lv; lv.x = lx; lv.y = ly; lv.z = lz; lv.w = lw;
    *(ushort4*)&Oh[base] = hv;
    *(ushort4*)&Ol[base] = lv;
}

// ---------------- query head: 2 queries per wave; fp16 gathers; uniform indices ----------------

__global__ __launch_bounds__(256) void query_kernel(
    const int* __restrict__ qry, const u16* __restrict__ Ptop,
    const u16* __restrict__ Pbot, const float* __restrict__ Wm2,
    const float* __restrict__ bm2, float* __restrict__ out)
{
    int q = (blockIdx.x * 4 + (threadIdx.x >> 6)) * 2;
    if (q >= NQ) return;
    int lane = threadIdx.x & 63;
    int a0 = __builtin_amdgcn_readfirstlane(qry[q * 2 + 0]);
    int b0 = __builtin_amdgcn_readfirstlane(qry[q * 2 + 1]);
    int a1 = __builtin_amdgcn_readfirstlane(qry[q * 2 + 2]);
    int b1 = __builtin_amdgcn_readfirstlane(qry[q * 2 + 3]);
    float4 w  = *(const float4*)&Wm2[lane * 4];
    float4 t0 = ld4h(&Ptop[(size_t)a0 * HD + lane * 4]);
    float4 v0 = ld4h(&Pbot[(size_t)b0 * HD + lane * 4]);
    float4 t1 = ld4h(&Ptop[(size_t)a1 * HD + lane * 4]);
    float4 v1 = ld4h(&Pbot[(size_t)b1 * HD + lane * 4]);
    float s0 = fmaxf(t0.x + v0.x, 0.f) * w.x + fmaxf(t0.y + v0.y, 0.f) * w.y
             + fmaxf(t0.z + v0.z, 0.f) * w.z + fmaxf(t0.w + v0.w, 0.f) * w.w;
    float s1 = fmaxf(t1.x + v1.x, 0.f) * w.x + fmaxf(t1.y + v1.y, 0.f) * w.y
             + fmaxf(t1.z + v1.z, 0.f) * w.z + fmaxf(t1.w + v1.w, 0.f) * w.w;
#pragma unroll
    for (int off = 32; off > 0; off >>= 1) {
        s0 += __shfl_down(s0, off, 64);
        s1 += __shfl_down(s1, off, 64);
    }
    if (lane == 0) {
        float bb = bm2[0];
        out[q] = fmaxf(s0 + bb, 0.f);
        if (q + 1 < NQ) out[q + 1] = fmaxf(s1 + bb, 0.f);
    }
}

// ---------------- launch ----------------

extern "C" void kernel_launch(void* const* d_in, const int* in_sizes, int n_in,
                              void* d_out, int out_size, void* d_ws, size_t ws_size,
                              hipStream_t stream) {
    const float* x    = (const float*)d_in[0];
    const int*   ei   = (const int*)d_in[1];
    const int*   qry  = (const int*)d_in[2];
    const float* W1l  = (const float*)d_in[3];
    const float* b1l  = (const float*)d_in[4];
    const float* W1r  = (const float*)d_in[5];
    const float* b1r  = (const float*)d_in[6];
    const float* att1 = (const float*)d_in[7];
    const float* W2l  = (const float*)d_in[8];
    const float* b2l  = (const float*)d_in[9];
    const float* W2r  = (const float*)d_in[10];
    const float* b2r  = (const float*)d_in[11];
    const float* att2 = (const float*)d_in[12];
    const float* Wm1  = (const float*)d_in[13];
    const float* bm1  = (const float*)d_in[14];
    const float* Wm2  = (const float*)d_in[15];
    const float* bm2  = (const float*)d_in[16];
    float* out = (float*)d_out;

    // workspace carve-up
    const size_t NND = (size_t)NN * DD;          // 12.5M floats
    u16* xl16    = (u16*)d_ws;                   // NN*256 halfs (25.6 MB)
    float* xr    = (float*)(xl16 + (size_t)NN * 256);  // NN*250 floats (50 MB)
    int* rowptr  = (int*)(xr + NND);             // NN+1
    int* fill    = rowptr + NN + 1;              // NN (count buffer)
    int* ssrc    = fill + NN;                    // ET
    int* bsum    = ssrc + ET;                    // 256
    uintptr_t wp = (uintptr_t)(bsum + 256);
    wp = (wp + 63) & ~(uintptr_t)63;
    u16* W1lTh = (u16*)wp;                       // 256*128 each
    u16* W1lTl = W1lTh + 256 * 128;
    u16* W1rTh = W1lTl + 256 * 128;
    u16* W1rTl = W1rTh + 256 * 128;
    u16* W2lTh = W1rTl + 256 * 128;              // 256*256 each from here
    u16* W2lTl = W2lTh + 65536;
    u16* W2rTh = W2lTl + 65536;
    u16* W2rTl = W2rTh + 65536;
    u16* WmtTh = W2rTl + 65536;
    u16* WmtTl = WmtTh + 65536;
    u16* WmbTh = WmtTl + 65536;
    u16* WmbTl = WmbTh + 65536;
    u16* Asph  = WmbTl + 65536;                  // NN*256 (also holds x-split [NN][128] early)
    u16* Aspl  = Asph + (size_t)NN * 256;
    // head fp16 buffers overlay xl16 / xr (both dead after layer-2 fused_edge)
    u16* Ptop16 = xl16;                          // NN*256 halfs
    u16* Pbot16 = (u16*)xr;                      // NN*256 halfs

    dim3 blk(256);
    int gET = (ET + 255) / 256;
    int gNode = (NN + 3) / 4;
    int nb = (NN + 255) / 256;                   // 196 scan blocks
    dim3 gg((NN + 127) / 128, 2, 2);             // rows x col-tiles x {C0,C1}

    // ---- conversions + fill zeroing (one dispatch) ----
    conv_all<<<CONVX_BLOCKS + 1280, blk, 0, stream>>>(x, fill, Asph, Aspl,
        W1l, W1r, W2l, W2r, Wm1,
        W1lTh, W1lTl, W1rTh, W1rTl, W2lTh, W2lTl, W2rTh, W2rTl,
        WmtTh, WmtTl, WmbTh, WmbTl);

    // ---- CSR build ----
    count_kernel<<<gET, blk, 0, stream>>>(ei, fill);
    scan1_kernel<<<nb, blk, 0, stream>>>(fill, rowptr, bsum);   // also zeroes fill
    scan2_kernel<<<1, blk, 0, stream>>>(bsum, rowptr, nb);
    scan3_kernel<<<nb, blk, 0, stream>>>(rowptr, bsum);
    scatter_kernel<<<gET, blk, 0, stream>>>(ei, rowptr, fill, ssrc);

    // ---- layer 1 (A = x-split, Kp=128): C0 = xl fp16, C1 = xr fp32 ----
    gemm_pair<<<gg, blk, 0, stream>>>(Asph, Aspl, 128, W1lTh, W1lTl, W1rTh, W1rTl,
                                      b1l, b1r, (void*)xl16, (void*)xr, NN, DD, 1);
    fused_edge_kernel<<<gNode, blk, 0, stream>>>(rowptr, ssrc, xl16, xr, att1, Asph, Aspl, 1);

    // ---- layer 2 (A = h-split, Kp=256) ----
    gemm_pair<<<gg, blk, 0, stream>>>(Asph, Aspl, 256, W2lTh, W2lTl, W2rTh, W2rTl,
                                      b2l, b2r, (void*)xl16, (void*)xr, NN, DD, 1);
    fused_edge_kernel<<<gNode, blk, 0, stream>>>(rowptr, ssrc, xl16, xr, att2, Asph, Aspl, 0);

    // ---- head precompute (A = emb-split, Kp=256): both outputs fp16 ----
    gemm_pair<<<gg, blk, 0, stream>>>(Asph, Aspl, 256, WmtTh, WmtTl, WmbTh, WmbTl,
                                      bm1, (const float*)nullptr, (void*)Ptop16, (void*)Pbot16, NN, HD, 3);

    // ---- per-query head ----
    query_kernel<<<(NQ / 2 + 3) / 4, blk, 0, stream>>>(qry, Ptop16, Pbot16, Wm2, bm2, out);
}

// Round 19
// 574.149 us; speedup vs baseline: 1.0657x; 1.0657x over previous
//
#include <hip/hip_runtime.h>
#include <hip/hip_fp16.h>
#include <math.h>
#include <stdint.h>

#define NN 50000
#define NE 800000
#define ET (NE + NN)      // 850000 edges incl self loops
#define FIN 128
#define DD 250
#define HD 256
#define NQ 200000
#define NEG_SLOPE 0.2f

typedef unsigned short u16;
typedef __attribute__((ext_vector_type(8))) short bf16x8;
typedef __attribute__((ext_vector_type(4))) float f32x4;
typedef _Float16 h2v __attribute__((ext_vector_type(2)));

__device__ __forceinline__ u16 f2bf_rne(float x) {
    unsigned int b = __float_as_uint(x);
    unsigned int r = (b + 0x7FFFu + ((b >> 16) & 1u)) >> 16;
    return (u16)r;
}
__device__ __forceinline__ void split2(float v, u16& h, u16& l) {
    unsigned int b = __float_as_uint(v);
    h = (u16)(b >> 16);
    float r = v - __uint_as_float(b & 0xFFFF0000u);
    l = f2bf_rne(r);
}
__device__ __forceinline__ u16 f2h(float v) {
    __half h = __float2half(v);
    return *reinterpret_cast<u16*>(&h);
}
// load 4 fp16 (8B) -> float4 (used by query kernel)
__device__ __forceinline__ float4 ld4h(const u16* p) {
    uint2 r = *(const uint2*)p;
    __half2 a = *(__half2*)&r.x;
    __half2 b = *(__half2*)&r.y;
    float2 fa = __half22float2(a), fb = __half22float2(b);
    return make_float4(fa.x, fa.y, fb.x, fb.y);
}
// packed fp16 max -> v_pk_max_f16 (avoids ROCm __hmax2 header overload issues)
__device__ __forceinline__ h2v hmax2v(h2v a, h2v b) {
    return __builtin_elementwise_max(a, b);
}

// ---------------- CSR build ----------------

__global__ void count_kernel(const int* __restrict__ ei, int* __restrict__ cnt) {
    int k = blockIdx.x * 256 + threadIdx.x;
    if (k >= ET) return;
    int d = (k < NE) ? ei[NE + k] : (k - NE);
    atomicAdd(&cnt[d], 1);
}

__global__ __launch_bounds__(256) void scan1_kernel(
    int* __restrict__ cnt, int* __restrict__ rowptr, int* __restrict__ bsum)
{
    __shared__ int buf[256];
    int t = threadIdx.x;
    int i = blockIdx.x * 256 + t;
    int v = (i < NN) ? cnt[i] : 0;
    if (i < NN) cnt[i] = 0;          // zero fill for scatter
    buf[t] = v;
    __syncthreads();
#pragma unroll
    for (int off = 1; off < 256; off <<= 1) {
        int add = (t >= off) ? buf[t - off] : 0;
        __syncthreads();
        buf[t] += add;
        __syncthreads();
    }
    if (i < NN) rowptr[i] = buf[t] - v;     // block-local exclusive
    if (t == 255) bsum[blockIdx.x] = buf[255];
}

__global__ __launch_bounds__(256) void scan2_kernel(
    int* __restrict__ bsum, int* __restrict__ rowptr, int nb)
{
    __shared__ int buf[256];
    int t = threadIdx.x;
    int v = (t < nb) ? bsum[t] : 0;
    buf[t] = v;
    __syncthreads();
#pragma unroll
    for (int off = 1; off < 256; off <<= 1) {
        int add = (t >= off) ? buf[t - off] : 0;
        __syncthreads();
        buf[t] += add;
        __syncthreads();
    }
    if (t < nb) bsum[t] = buf[t] - v;
    if (t == 255) rowptr[NN] = buf[255];
}

__global__ __launch_bounds__(256) void scan3_kernel(
    int* __restrict__ rowptr, const int* __restrict__ bsum)
{
    int i = blockIdx.x * 256 + threadIdx.x;
    if (i < NN) rowptr[i] += bsum[blockIdx.x];
}

// stores premultiplied src BYTE offset (s*512, fp16-row stride) for the fused kernel
__global__ void scatter_kernel(const int* __restrict__ ei,
                               const int* __restrict__ rowptr,
                               int* __restrict__ fill,
                               int* __restrict__ ssrc) {
    int k = blockIdx.x * 256 + threadIdx.x;
    if (k >= ET) return;
    int s, d;
    if (k < NE) { s = ei[k]; d = ei[NE + k]; }
    else        { s = k - NE; d = k - NE; }
    int pos = rowptr[d] + atomicAdd(&fill[d], 1);
    ssrc[pos] = s << 9;
}

// ---------------- combined conversion kernel ----------------

#define CONVX_BLOCKS 3125

__global__ __launch_bounds__(256) void conv_all(
    const float* __restrict__ x, int* __restrict__ fill,
    u16* __restrict__ Ah, u16* __restrict__ Al,
    const float* __restrict__ W1l, const float* __restrict__ W1r,
    const float* __restrict__ W2l, const float* __restrict__ W2r,
    const float* __restrict__ Wm1,
    u16* __restrict__ W1lTh, u16* __restrict__ W1lTl,
    u16* __restrict__ W1rTh, u16* __restrict__ W1rTl,
    u16* __restrict__ W2lTh, u16* __restrict__ W2lTl,
    u16* __restrict__ W2rTh, u16* __restrict__ W2rTl,
    u16* __restrict__ WmtTh, u16* __restrict__ WmtTl,
    u16* __restrict__ WmbTh, u16* __restrict__ WmbTl)
{
    if (blockIdx.x < CONVX_BLOCKS) {
        int tid = blockIdx.x * 256 + threadIdx.x;
        if (tid < NN) fill[tid] = 0;
        size_t idx = (size_t)tid * 8;
        if (idx >= (size_t)NN * FIN) return;
        float4 v0 = *(const float4*)(x + idx);
        float4 v1 = *(const float4*)(x + idx + 4);
        float vv[8] = {v0.x, v0.y, v0.z, v0.w, v1.x, v1.y, v1.z, v1.w};
        bf16x8 h, l;
#pragma unroll
        for (int j = 0; j < 8; j++) {
            u16 hh, ll;
            split2(vv[j], hh, ll);
            h[j] = (short)hh; l[j] = (short)ll;
        }
        *(bf16x8*)(Ah + idx) = h;
        *(bf16x8*)(Al + idx) = l;
        return;
    }
    int b = blockIdx.x - CONVX_BLOCKS;
    const float* W; int K, N, koff, kshift, b0; u16 *oh, *ol;
    if (b < 128)       { W = W1l; K = FIN; N = DD; koff = 0;  kshift = 7; b0 = 0;    oh = W1lTh; ol = W1lTl; }
    else if (b < 256)  { W = W1r; K = FIN; N = DD; koff = 0;  kshift = 7; b0 = 128;  oh = W1rTh; ol = W1rTl; }
    else if (b < 512)  { W = W2l; K = DD;  N = DD; koff = 0;  kshift = 8; b0 = 256;  oh = W2lTh; ol = W2lTl; }
    else if (b < 768)  { W = W2r; K = DD;  N = DD; koff = 0;  kshift = 8; b0 = 512;  oh = W2rTh; ol = W2rTl; }
    else if (b < 1024) { W = Wm1; K = DD;  N = HD; koff = 0;  kshift = 8; b0 = 768;  oh = WmtTh; ol = WmtTl; }
    else               { W = Wm1; K = DD;  N = HD; koff = DD; kshift = 8; b0 = 1024; oh = WmbTh; ol = WmbTl; }
    int id = (b - b0) * 256 + threadIdx.x;
    int Kp = 1 << kshift;
    int n = id >> kshift, k = id & (Kp - 1);
    float v = (n < N && k < K) ? W[(size_t)(k + koff) * N + n] : 0.f;
    u16 h, l;
    split2(v, h, l);
    oh[id] = h;
    ol[id] = l;
}

// ---------------- pre-split bf16 MFMA pair-GEMM, register double-buffered ----------------
// A and B staged in LDS (AP=40 padding). K-tile t+1's global loads are issued into
// registers right after the barrier, overlapping the MFMA burst of tile t (hides
// the ~300-400cy global latency that serialized the R14/R16 K-loop).
// fmt bit0: C0 as fp16 stride-256; bit1: C1 as fp16 stride-256; else fp32 stride-N

#define AP 40   // padded LDS row length (u16)

__global__ __launch_bounds__(256, 2) void gemm_pair(
    const u16* __restrict__ Ah, const u16* __restrict__ Al, int Kp,
    const u16* __restrict__ B0h, const u16* __restrict__ B0l,
    const u16* __restrict__ B1h, const u16* __restrict__ B1l,
    const float* __restrict__ bias0, const float* __restrict__ bias1,
    void* __restrict__ C0v, void* __restrict__ C1v, int M, int N, int fmt)
{
    __shared__ u16 AhS[128][AP], AlS[128][AP];
    __shared__ u16 BhS[2][128][AP], BlS[2][128][AP];

    int row0 = blockIdx.x * 128;
    int col0 = blockIdx.y * 128;
    int t = threadIdx.x;
    int lane = t & 63, w = t >> 6;
    int wr = w >> 1, wc = w & 1;
    int quad = lane >> 4, rr = lane & 15;

    f32x4 acc0[4][4], acc1[4][4];
#pragma unroll
    for (int i = 0; i < 4; i++)
#pragma unroll
        for (int j = 0; j < 4; j++) {
            acc0[i][j] = (f32x4){0.f, 0.f, 0.f, 0.f};
            acc1[i][j] = (f32x4){0.f, 0.f, 0.f, 0.f};
        }

    int ar = t >> 1, akh = (t & 1) * 16;
    int gr = row0 + ar;
    int nB = col0 + ar;
    const u16* pAh = Ah + (size_t)gr * Kp + akh;
    const u16* pAl = Al + (size_t)gr * Kp + akh;
    const u16* pB0h = B0h + (size_t)nB * Kp + akh;
    const u16* pB0l = B0l + (size_t)nB * Kp + akh;
    const u16* pB1h = B1h + (size_t)nB * Kp + akh;
    const u16* pB1l = B1l + (size_t)nB * Kp + akh;

    // prefetch tile 0 into registers
    bf16x8 rah0{}, rah1{}, ral0{}, ral1{};
    if (gr < M) {
        rah0 = *(const bf16x8*)(pAh);
        rah1 = *(const bf16x8*)(pAh + 8);
        ral0 = *(const bf16x8*)(pAl);
        ral1 = *(const bf16x8*)(pAl + 8);
    }
    bf16x8 rb0h0 = *(const bf16x8*)(pB0h), rb0h1 = *(const bf16x8*)(pB0h + 8);
    bf16x8 rb0l0 = *(const bf16x8*)(pB0l), rb0l1 = *(const bf16x8*)(pB0l + 8);
    bf16x8 rb1h0 = *(const bf16x8*)(pB1h), rb1h1 = *(const bf16x8*)(pB1h + 8);
    bf16x8 rb1l0 = *(const bf16x8*)(pB1l), rb1l1 = *(const bf16x8*)(pB1l + 8);

    for (int k0 = 0; k0 < Kp; k0 += 32) {
        __syncthreads();   // prior iteration's LDS reads complete
        *(bf16x8*)&AhS[ar][akh]     = rah0;
        *(bf16x8*)&AhS[ar][akh + 8] = rah1;
        *(bf16x8*)&AlS[ar][akh]     = ral0;
        *(bf16x8*)&AlS[ar][akh + 8] = ral1;
        *(bf16x8*)&BhS[0][ar][akh]     = rb0h0;
        *(bf16x8*)&BhS[0][ar][akh + 8] = rb0h1;
        *(bf16x8*)&BlS[0][ar][akh]     = rb0l0;
        *(bf16x8*)&BlS[0][ar][akh + 8] = rb0l1;
        *(bf16x8*)&BhS[1][ar][akh]     = rb1h0;
        *(bf16x8*)&BhS[1][ar][akh + 8] = rb1h1;
        *(bf16x8*)&BlS[1][ar][akh]     = rb1l0;
        *(bf16x8*)&BlS[1][ar][akh + 8] = rb1l1;
        __syncthreads();   // LDS tile ready

        // prefetch next tile into registers (overlaps the MFMA burst below)
        int kn = k0 + 32;
        if (kn < Kp) {
            if (gr < M) {
                rah0 = *(const bf16x8*)(pAh + kn);
                rah1 = *(const bf16x8*)(pAh + kn + 8);
                ral0 = *(const bf16x8*)(pAl + kn);
                ral1 = *(const bf16x8*)(pAl + kn + 8);
            }
            rb0h0 = *(const bf16x8*)(pB0h + kn); rb0h1 = *(const bf16x8*)(pB0h + kn + 8);
            rb0l0 = *(const bf16x8*)(pB0l + kn); rb0l1 = *(const bf16x8*)(pB0l + kn + 8);
            rb1h0 = *(const bf16x8*)(pB1h + kn); rb1h1 = *(const bf16x8*)(pB1h + kn + 8);
            rb1l0 = *(const bf16x8*)(pB1l + kn); rb1l1 = *(const bf16x8*)(pB1l + kn + 8);
        }

        bf16x8 fAh[4], fAl[4];
#pragma unroll
        for (int fi = 0; fi < 4; fi++) {
            int r = wr * 64 + fi * 16 + rr;
            fAh[fi] = *(const bf16x8*)&AhS[r][quad * 8];
            fAl[fi] = *(const bf16x8*)&AlS[r][quad * 8];
        }
#pragma unroll
        for (int fj = 0; fj < 4; fj++) {
            int c = wc * 64 + fj * 16 + rr;
            bf16x8 b0h = *(const bf16x8*)&BhS[0][c][quad * 8];
            bf16x8 b0l = *(const bf16x8*)&BlS[0][c][quad * 8];
            bf16x8 b1h = *(const bf16x8*)&BhS[1][c][quad * 8];
            bf16x8 b1l = *(const bf16x8*)&BlS[1][c][quad * 8];
#pragma unroll
            for (int fi = 0; fi < 4; fi++) {
                acc0[fi][fj] = __builtin_amdgcn_mfma_f32_16x16x32_bf16(fAh[fi], b0h, acc0[fi][fj], 0, 0, 0);
                acc0[fi][fj] = __builtin_amdgcn_mfma_f32_16x16x32_bf16(fAh[fi], b0l, acc0[fi][fj], 0, 0, 0);
                acc0[fi][fj] = __builtin_amdgcn_mfma_f32_16x16x32_bf16(fAl[fi], b0h, acc0[fi][fj], 0, 0, 0);
                acc1[fi][fj] = __builtin_amdgcn_mfma_f32_16x16x32_bf16(fAh[fi], b1h, acc1[fi][fj], 0, 0, 0);
                acc1[fi][fj] = __builtin_amdgcn_mfma_f32_16x16x32_bf16(fAh[fi], b1l, acc1[fi][fj], 0, 0, 0);
                acc1[fi][fj] = __builtin_amdgcn_mfma_f32_16x16x32_bf16(fAl[fi], b1h, acc1[fi][fj], 0, 0, 0);
            }
        }
    }

#pragma unroll
    for (int fj = 0; fj < 4; fj++) {
        int gc = col0 + wc * 64 + fj * 16 + rr;
        if (gc >= N) continue;
        float bb0 = bias0 ? bias0[gc] : 0.f;
        float bb1 = bias1 ? bias1[gc] : 0.f;
#pragma unroll
        for (int fi = 0; fi < 4; fi++) {
#pragma unroll
            for (int r = 0; r < 4; r++) {
                int grr = row0 + wr * 64 + fi * 16 + quad * 4 + r;
                if (grr < M) {
                    float v0 = acc0[fi][fj][r] + bb0;
                    float v1 = acc1[fi][fj][r] + bb1;
                    if (fmt & 1) ((u16*)C0v)[(size_t)grr * 256 + gc] = f2h(v0);
                    else         ((float*)C0v)[(size_t)grr * N + gc] = v0;
                    if (fmt & 2) ((u16*)C1v)[(size_t)grr * 256 + gc] = f2h(v1);
                    else         ((float*)C1v)[(size_t)grr * N + gc] = v1;
                }
            }
        }
    }
}

// ---------------- fused edge phase: packed-fp16 single-pass softmax+aggregate ----------------
// 4-edge unroll full-wave. Wave-uniform scalarization: beg/end/ssrc offsets go through
// readfirstlane so edge offsets live in SGPRs (s_load + saddr addressing, ~0 VALU/load).

__global__ __launch_bounds__(256) void fused_edge_kernel(
    const int* __restrict__ rowptr, const int* __restrict__ ssrc,
    const u16* __restrict__ xl16, const float* __restrict__ xr,
    const float* __restrict__ att,
    u16* __restrict__ Oh, u16* __restrict__ Ol, int dorelu)
{
    int i = blockIdx.x * 4 + (threadIdx.x >> 6);
    if (i >= NN) return;
    int lane = threadIdx.x & 63;
    int beg = __builtin_amdgcn_readfirstlane(rowptr[i]);
    int end = __builtin_amdgcn_readfirstlane(rowptr[i + 1]);
    int d0 = lane * 4;
    int lb = d0 * 2;                 // lane byte offset into fp16 row

    // masked fp32 loads of xr/att for this lane's 4 dims, converted to fp16 pairs
    float xrf[4] = {0.f, 0.f, 0.f, 0.f};
    float atf[4] = {0.f, 0.f, 0.f, 0.f};
#pragma unroll
    for (int j = 0; j < 4; j++) {
        if (d0 + j < DD) {
            xrf[j] = xr[(size_t)i * DD + d0 + j];
            atf[j] = att[d0 + j];
        }
    }
    h2v xr0h, xr1h, at0h, at1h;
    xr0h.x = (_Float16)xrf[0]; xr0h.y = (_Float16)xrf[1];
    xr1h.x = (_Float16)xrf[2]; xr1h.y = (_Float16)xrf[3];
    at0h.x = (_Float16)atf[0]; at0h.y = (_Float16)atf[1];
    at1h.x = (_Float16)atf[2]; at1h.y = (_Float16)atf[3];
    const h2v c02 = {(_Float16)0.2f, (_Float16)0.2f};

    const char* xlb = (const char*)xl16;

    float m = -1e30f, ssum = 0.f;
    float4 acc = make_float4(0.f, 0.f, 0.f, 0.f);

    int p = beg;
    for (; p + 3 < end; p += 4) {
        int o0 = __builtin_amdgcn_readfirstlane(ssrc[p]);
        int o1 = __builtin_amdgcn_readfirstlane(ssrc[p + 1]);
        int o2 = __builtin_amdgcn_readfirstlane(ssrc[p + 2]);
        int o3 = __builtin_amdgcn_readfirstlane(ssrc[p + 3]);
        uint2 r0 = *(const uint2*)(xlb + o0 + lb);
        uint2 r1 = *(const uint2*)(xlb + o1 + lb);
        uint2 r2 = *(const uint2*)(xlb + o2 + lb);
        uint2 r3 = *(const uint2*)(xlb + o3 + lb);
        h2v x00 = *(h2v*)&r0.x, x01 = *(h2v*)&r0.y;
        h2v x10 = *(h2v*)&r1.x, x11 = *(h2v*)&r1.y;
        h2v x20 = *(h2v*)&r2.x, x21 = *(h2v*)&r2.y;
        h2v x30 = *(h2v*)&r3.x, x31 = *(h2v*)&r3.y;

        h2v s;
        float e0, e1, e2, e3;
        s = x00 + xr0h; s = hmax2v(s, s * c02);
        e0 = __builtin_amdgcn_fdot2(s, at0h, 0.f, false);
        s = x01 + xr1h; s = hmax2v(s, s * c02);
        e0 = __builtin_amdgcn_fdot2(s, at1h, e0, false);
        s = x10 + xr0h; s = hmax2v(s, s * c02);
        e1 = __builtin_amdgcn_fdot2(s, at0h, 0.f, false);
        s = x11 + xr1h; s = hmax2v(s, s * c02);
        e1 = __builtin_amdgcn_fdot2(s, at1h, e1, false);
        s = x20 + xr0h; s = hmax2v(s, s * c02);
        e2 = __builtin_amdgcn_fdot2(s, at0h, 0.f, false);
        s = x21 + xr1h; s = hmax2v(s, s * c02);
        e2 = __builtin_amdgcn_fdot2(s, at1h, e2, false);
        s = x30 + xr0h; s = hmax2v(s, s * c02);
        e3 = __builtin_amdgcn_fdot2(s, at0h, 0.f, false);
        s = x31 + xr1h; s = hmax2v(s, s * c02);
        e3 = __builtin_amdgcn_fdot2(s, at1h, e3, false);

#pragma unroll
        for (int off = 1; off < 64; off <<= 1) {
            e0 += __shfl_xor(e0, off, 64);
            e1 += __shfl_xor(e1, off, 64);
            e2 += __shfl_xor(e2, off, 64);
            e3 += __shfl_xor(e3, off, 64);
        }
        float nm = fmaxf(fmaxf(m, e0), fmaxf(fmaxf(e1, e2), e3));
        float sc = __expf(m - nm);
        float w0 = __expf(e0 - nm);
        float w1 = __expf(e1 - nm);
        float w2 = __expf(e2 - nm);
        float w3 = __expf(e3 - nm);
        // tree-paired accumulate (short dep chains; fma_mix folds the h->f cvt)
        float ax0 = fmaf(w1, (float)x10.x, w0 * (float)x00.x);
        float ax1 = fmaf(w3, (float)x30.x, w2 * (float)x20.x);
        float ay0 = fmaf(w1, (float)x10.y, w0 * (float)x00.y);
        float ay1 = fmaf(w3, (float)x30.y, w2 * (float)x20.y);
        float az0 = fmaf(w1, (float)x11.x, w0 * (float)x01.x);
        float az1 = fmaf(w3, (float)x31.x, w2 * (float)x21.x);
        float aw0 = fmaf(w1, (float)x11.y, w0 * (float)x01.y);
        float aw1 = fmaf(w3, (float)x31.y, w2 * (float)x21.y);
        acc.x = fmaf(acc.x, sc, ax0 + ax1);
        acc.y = fmaf(acc.y, sc, ay0 + ay1);
        acc.z = fmaf(acc.z, sc, az0 + az1);
        acc.w = fmaf(acc.w, sc, aw0 + aw1);
        ssum = fmaf(ssum, sc, (w0 + w1) + (w2 + w3));
        m = nm;
    }
    for (; p < end; p++) {
        int o = __builtin_amdgcn_readfirstlane(ssrc[p]);
        uint2 r = *(const uint2*)(xlb + o + lb);
        h2v x0 = *(h2v*)&r.x, x1 = *(h2v*)&r.y;
        h2v s;
        float e;
        s = x0 + xr0h; s = hmax2v(s, s * c02);
        e = __builtin_amdgcn_fdot2(s, at0h, 0.f, false);
        s = x1 + xr1h; s = hmax2v(s, s * c02);
        e = __builtin_amdgcn_fdot2(s, at1h, e, false);
#pragma unroll
        for (int off = 1; off < 64; off <<= 1)
            e += __shfl_xor(e, off, 64);
        float nm = fmaxf(m, e);
        float sc = __expf(m - nm);
        float w = __expf(e - nm);
        acc.x = fmaf(w, (float)x0.x, acc.x * sc);
        acc.y = fmaf(w, (float)x0.y, acc.y * sc);
        acc.z = fmaf(w, (float)x1.x, acc.z * sc);
        acc.w = fmaf(w, (float)x1.y, acc.w * sc);
        ssum = fmaf(ssum, sc, w);
        m = nm;
    }

    float inv = 1.f / ssum;
    acc.x *= inv; acc.y *= inv; acc.z *= inv; acc.w *= inv;
    if (dorelu) {
        acc.x = fmaxf(acc.x, 0.f); acc.y = fmaxf(acc.y, 0.f);
        acc.z = fmaxf(acc.z, 0.f); acc.w = fmaxf(acc.w, 0.f);
    }
    size_t base = (size_t)i * 256 + d0;
    u16 hx, lx, hy, ly, hz, lz, hw, lw;
    split2(acc.x, hx, lx); split2(acc.y, hy, ly);
    split2(acc.z, hz, lz); split2(acc.w, hw, lw);
    ushort4 hv; hv.x = hx; hv.y = hy; hv.z = hz; hv.w = hw;
    ushort4 lv; lv.x = lx; lv.y = ly; lv.z = lz; lv.w = lw;
    *(ushort4*)&Oh[base] = hv;
    *(ushort4*)&Ol[base] = lv;
}

// ---------------- query head: 2 queries per wave; fp16 gathers; uniform indices ----------------

__global__ __launch_bounds__(256) void query_kernel(
    const int* __restrict__ qry, const u16* __restrict__ Ptop,
    const u16* __restrict__ Pbot, const float* __restrict__ Wm2,
    const float* __restrict__ bm2, float* __restrict__ out)
{
    int q = (blockIdx.x * 4 + (threadIdx.x >> 6)) * 2;
    if (q >= NQ) return;
    int lane = threadIdx.x & 63;
    int a0 = __builtin_amdgcn_readfirstlane(qry[q * 2 + 0]);
    int b0 = __builtin_amdgcn_readfirstlane(qry[q * 2 + 1]);
    int a1 = __builtin_amdgcn_readfirstlane(qry[q * 2 + 2]);
    int b1 = __builtin_amdgcn_readfirstlane(qry[q * 2 + 3]);
    float4 w  = *(const float4*)&Wm2[lane * 4];
    float4 t0 = ld4h(&Ptop[(size_t)a0 * HD + lane * 4]);
    float4 v0 = ld4h(&Pbot[(size_t)b0 * HD + lane * 4]);
    float4 t1 = ld4h(&Ptop[(size_t)a1 * HD + lane * 4]);
    float4 v1 = ld4h(&Pbot[(size_t)b1 * HD + lane * 4]);
    float s0 = fmaxf(t0.x + v0.x, 0.f) * w.x + fmaxf(t0.y + v0.y, 0.f) * w.y
             + fmaxf(t0.z + v0.z, 0.f) * w.z + fmaxf(t0.w + v0.w, 0.f) * w.w;
    float s1 = fmaxf(t1.x + v1.x, 0.f) * w.x + fmaxf(t1.y + v1.y, 0.f) * w.y
             + fmaxf(t1.z + v1.z, 0.f) * w.z + fmaxf(t1.w + v1.w, 0.f) * w.w;
#pragma unroll
    for (int off = 32; off > 0; off >>= 1) {
        s0 += __shfl_down(s0, off, 64);
        s1 += __shfl_down(s1, off, 64);
    }
    if (lane == 0) {
        float bb = bm2[0];
        out[q] = fmaxf(s0 + bb, 0.f);
        if (q + 1 < NQ) out[q + 1] = fmaxf(s1 + bb, 0.f);
    }
}

// ---------------- launch ----------------

extern "C" void kernel_launch(void* const* d_in, const int* in_sizes, int n_in,
                              void* d_out, int out_size, void* d_ws, size_t ws_size,
                              hipStream_t stream) {
    const float* x    = (const float*)d_in[0];
    const int*   ei   = (const int*)d_in[1];
    const int*   qry  = (const int*)d_in[2];
    const float* W1l  = (const float*)d_in[3];
    const float* b1l  = (const float*)d_in[4];
    const float* W1r  = (const float*)d_in[5];
    const float* b1r  = (const float*)d_in[6];
    const float* att1 = (const float*)d_in[7];
    const float* W2l  = (const float*)d_in[8];
    const float* b2l  = (const float*)d_in[9];
    const float* W2r  = (const float*)d_in[10];
    const float* b2r  = (const float*)d_in[11];
    const float* att2 = (const float*)d_in[12];
    const float* Wm1  = (const float*)d_in[13];
    const float* bm1  = (const float*)d_in[14];
    const float* Wm2  = (const float*)d_in[15];
    const float* bm2  = (const float*)d_in[16];
    float* out = (float*)d_out;

    // workspace carve-up
    const size_t NND = (size_t)NN * DD;          // 12.5M floats
    u16* xl16    = (u16*)d_ws;                   // NN*256 halfs (25.6 MB)
    float* xr    = (float*)(xl16 + (size_t)NN * 256);  // NN*250 floats (50 MB)
    int* rowptr  = (int*)(xr + NND);             // NN+1
    int* fill    = rowptr + NN + 1;              // NN (count buffer)
    int* ssrc    = fill + NN;                    // ET
    int* bsum    = ssrc + ET;                    // 256
    uintptr_t wp = (uintptr_t)(bsum + 256);
    wp = (wp + 63) & ~(uintptr_t)63;
    u16* W1lTh = (u16*)wp;                       // 256*128 each
    u16* W1lTl = W1lTh + 256 * 128;
    u16* W1rTh = W1lTl + 256 * 128;
    u16* W1rTl = W1rTh + 256 * 128;
    u16* W2lTh = W1rTl + 256 * 128;              // 256*256 each from here
    u16* W2lTl = W2lTh + 65536;
    u16* W2rTh = W2lTl + 65536;
    u16* W2rTl = W2rTh + 65536;
    u16* WmtTh = W2rTl + 65536;
    u16* WmtTl = WmtTh + 65536;
    u16* WmbTh = WmtTl + 65536;
    u16* WmbTl = WmbTh + 65536;
    u16* Asph  = WmbTl + 65536;                  // NN*256 (also holds x-split [NN][128] early)
    u16* Aspl  = Asph + (size_t)NN * 256;
    // head fp16 buffers overlay xl16 / xr (both dead after layer-2 fused_edge)
    u16* Ptop16 = xl16;                          // NN*256 halfs
    u16* Pbot16 = (u16*)xr;                      // NN*256 halfs

    dim3 blk(256);
    int gET = (ET + 255) / 256;
    int gNode = (NN + 3) / 4;
    int nb = (NN + 255) / 256;                   // 196 scan blocks
    dim3 gg((NN + 127) / 128, 2);

    // ---- conversions + fill zeroing (one dispatch) ----
    conv_all<<<CONVX_BLOCKS + 1280, blk, 0, stream>>>(x, fill, Asph, Aspl,
        W1l, W1r, W2l, W2r, Wm1,
        W1lTh, W1lTl, W1rTh, W1rTl, W2lTh, W2lTl, W2rTh, W2rTl,
        WmtTh, WmtTl, WmbTh, WmbTl);

    // ---- CSR build ----
    count_kernel<<<gET, blk, 0, stream>>>(ei, fill);
    scan1_kernel<<<nb, blk, 0, stream>>>(fill, rowptr, bsum);   // also zeroes fill
    scan2_kernel<<<1, blk, 0, stream>>>(bsum, rowptr, nb);
    scan3_kernel<<<nb, blk, 0, stream>>>(rowptr, bsum);
    scatter_kernel<<<gET, blk, 0, stream>>>(ei, rowptr, fill, ssrc);

    // ---- layer 1 (A = x-split, Kp=128): C0 = xl fp16, C1 = xr fp32 ----
    gemm_pair<<<gg, blk, 0, stream>>>(Asph, Aspl, 128, W1lTh, W1lTl, W1rTh, W1rTl,
                                      b1l, b1r, (void*)xl16, (void*)xr, NN, DD, 1);
    fused_edge_kernel<<<gNode, blk, 0, stream>>>(rowptr, ssrc, xl16, xr, att1, Asph, Aspl, 1);

    // ---- layer 2 (A = h-split, Kp=256) ----
    gemm_pair<<<gg, blk, 0, stream>>>(Asph, Aspl, 256, W2lTh, W2lTl, W2rTh, W2rTl,
                                      b2l, b2r, (void*)xl16, (void*)xr, NN, DD, 1);
    fused_edge_kernel<<<gNode, blk, 0, stream>>>(rowptr, ssrc, xl16, xr, att2, Asph, Aspl, 0);

    // ---- head precompute (A = emb-split, Kp=256): both outputs fp16 ----
    gemm_pair<<<gg, blk, 0, stream>>>(Asph, Aspl, 256, WmtTh, WmtTl, WmbTh, WmbTl,
                                      bm1, (const float*)nullptr, (void*)Ptop16, (void*)Pbot16, NN, HD, 3);

    // ---- per-query head ----
    query_kernel<<<(NQ / 2 + 3) / 4, blk, 0, stream>>>(qry, Ptop16, Pbot16, Wm2, bm2, out);
}

// Round 20
// 541.312 us; speedup vs baseline: 1.1303x; 1.0607x over previous
//
#include <hip/hip_runtime.h>
#include <hip/hip_fp16.h>
#include <math.h>
#include <stdint.h>

#define NN 50000
#define NE 800000
#define ET (NE + NN)      // 850000 edges incl self loops
#define FIN 128
#define DD 250
#define HD 256
#define NQ 200000
#define NEG_SLOPE 0.2f

typedef unsigned short u16;
typedef __attribute__((ext_vector_type(4))) float f32x4;
typedef _Float16 h2v __attribute__((ext_vector_type(2)));
typedef _Float16 f16x8 __attribute__((ext_vector_type(8)));

__device__ __forceinline__ u16 f2h(float v) {
    __half h = __float2half(v);
    return *reinterpret_cast<u16*>(&h);
}
// load 4 fp16 (8B) -> float4 (used by query kernel)
__device__ __forceinline__ float4 ld4h(const u16* p) {
    uint2 r = *(const uint2*)p;
    __half2 a = *(__half2*)&r.x;
    __half2 b = *(__half2*)&r.y;
    float2 fa = __half22float2(a), fb = __half22float2(b);
    return make_float4(fa.x, fa.y, fb.x, fb.y);
}
// packed fp16 max -> v_pk_max_f16 (avoids ROCm __hmax2 header overload issues)
__device__ __forceinline__ h2v hmax2v(h2v a, h2v b) {
    return __builtin_elementwise_max(a, b);
}

// ---------------- CSR build ----------------

__global__ void count_kernel(const int* __restrict__ ei, int* __restrict__ cnt) {
    int k = blockIdx.x * 256 + threadIdx.x;
    if (k >= ET) return;
    int d = (k < NE) ? ei[NE + k] : (k - NE);
    atomicAdd(&cnt[d], 1);
}

__global__ __launch_bounds__(256) void scan1_kernel(
    int* __restrict__ cnt, int* __restrict__ rowptr, int* __restrict__ bsum)
{
    __shared__ int buf[256];
    int t = threadIdx.x;
    int i = blockIdx.x * 256 + t;
    int v = (i < NN) ? cnt[i] : 0;
    if (i < NN) cnt[i] = 0;          // zero fill for scatter
    buf[t] = v;
    __syncthreads();
#pragma unroll
    for (int off = 1; off < 256; off <<= 1) {
        int add = (t >= off) ? buf[t - off] : 0;
        __syncthreads();
        buf[t] += add;
        __syncthreads();
    }
    if (i < NN) rowptr[i] = buf[t] - v;     // block-local exclusive
    if (t == 255) bsum[blockIdx.x] = buf[255];
}

__global__ __launch_bounds__(256) void scan2_kernel(
    int* __restrict__ bsum, int* __restrict__ rowptr, int nb)
{
    __shared__ int buf[256];
    int t = threadIdx.x;
    int v = (t < nb) ? bsum[t] : 0;
    buf[t] = v;
    __syncthreads();
#pragma unroll
    for (int off = 1; off < 256; off <<= 1) {
        int add = (t >= off) ? buf[t - off] : 0;
        __syncthreads();
        buf[t] += add;
        __syncthreads();
    }
    if (t < nb) bsum[t] = buf[t] - v;
    if (t == 255) rowptr[NN] = buf[255];
}

__global__ __launch_bounds__(256) void scan3_kernel(
    int* __restrict__ rowptr, const int* __restrict__ bsum)
{
    int i = blockIdx.x * 256 + threadIdx.x;
    if (i < NN) rowptr[i] += bsum[blockIdx.x];
}

// stores premultiplied src BYTE offset (s*512, fp16-row stride) for the fused kernel
__global__ void scatter_kernel(const int* __restrict__ ei,
                               const int* __restrict__ rowptr,
                               int* __restrict__ fill,
                               int* __restrict__ ssrc) {
    int k = blockIdx.x * 256 + threadIdx.x;
    if (k >= ET) return;
    int s, d;
    if (k < NE) { s = ei[k]; d = ei[NE + k]; }
    else        { s = k - NE; d = k - NE; }
    int pos = rowptr[d] + atomicAdd(&fill[d], 1);
    ssrc[pos] = s << 9;
}

// ---------------- combined conversion kernel (all fp16 now) ----------------

#define CONVX_BLOCKS 3125

__global__ __launch_bounds__(256) void conv_all(
    const float* __restrict__ x, int* __restrict__ fill,
    u16* __restrict__ Asp,
    const float* __restrict__ W1l, const float* __restrict__ W1r,
    const float* __restrict__ W2l, const float* __restrict__ W2r,
    const float* __restrict__ Wm1,
    u16* __restrict__ W1lT, u16* __restrict__ W1rT,
    u16* __restrict__ W2lT, u16* __restrict__ W2rT,
    u16* __restrict__ WmtT, u16* __restrict__ WmbT)
{
    if (blockIdx.x < CONVX_BLOCKS) {
        int tid = blockIdx.x * 256 + threadIdx.x;
        if (tid < NN) fill[tid] = 0;
        size_t idx = (size_t)tid * 8;
        if (idx >= (size_t)NN * FIN) return;
        float4 v0 = *(const float4*)(x + idx);
        float4 v1 = *(const float4*)(x + idx + 4);
        ushort4 o0, o1;
        o0.x = f2h(v0.x); o0.y = f2h(v0.y); o0.z = f2h(v0.z); o0.w = f2h(v0.w);
        o1.x = f2h(v1.x); o1.y = f2h(v1.y); o1.z = f2h(v1.z); o1.w = f2h(v1.w);
        *(ushort4*)(Asp + idx) = o0;
        *(ushort4*)(Asp + idx + 4) = o1;
        return;
    }
    int b = blockIdx.x - CONVX_BLOCKS;
    const float* W; int K, N, koff, kshift, b0; u16* ot;
    if (b < 128)       { W = W1l; K = FIN; N = DD; koff = 0;  kshift = 7; b0 = 0;    ot = W1lT; }
    else if (b < 256)  { W = W1r; K = FIN; N = DD; koff = 0;  kshift = 7; b0 = 128;  ot = W1rT; }
    else if (b < 512)  { W = W2l; K = DD;  N = DD; koff = 0;  kshift = 8; b0 = 256;  ot = W2lT; }
    else if (b < 768)  { W = W2r; K = DD;  N = DD; koff = 0;  kshift = 8; b0 = 512;  ot = W2rT; }
    else if (b < 1024) { W = Wm1; K = DD;  N = HD; koff = 0;  kshift = 8; b0 = 768;  ot = WmtT; }
    else               { W = Wm1; K = DD;  N = HD; koff = DD; kshift = 8; b0 = 1024; ot = WmbT; }
    int id = (b - b0) * 256 + threadIdx.x;
    int Kp = 1 << kshift;
    int n = id >> kshift, k = id & (Kp - 1);
    float v = (n < N && k < K) ? W[(size_t)(k + koff) * N + n] : 0.f;
    ot[id] = f2h(v);
}

// ---------------- fp16 MFMA pair-GEMM ----------------
// Pure fp16 operands (fp32 accumulate): 1 MFMA per frag-pair per output, 3 LDS
// arrays (30KB). The 3-term split-bf16 version measured 83us; 4 schedule variants
// (B-direct, z-split, padding, reg-dbuf) all regressed -> attack arithmetic instead.
// fmt bit0: C0 as fp16 stride-256; bit1: C1 as fp16 stride-256; else fp32 stride-N

#define AP 40   // padded LDS row length (u16)

__global__ __launch_bounds__(256, 2) void gemm_pair(
    const u16* __restrict__ A, int Kp,
    const u16* __restrict__ B0, const u16* __restrict__ B1,
    const float* __restrict__ bias0, const float* __restrict__ bias1,
    void* __restrict__ C0v, void* __restrict__ C1v, int M, int N, int fmt)
{
    __shared__ u16 AS[128][AP], B0S[128][AP], B1S[128][AP];

    int row0 = blockIdx.x * 128;
    int col0 = blockIdx.y * 128;
    int t = threadIdx.x;
    int lane = t & 63, w = t >> 6;
    int wr = w >> 1, wc = w & 1;
    int quad = lane >> 4, rr = lane & 15;

    f32x4 acc0[4][4], acc1[4][4];
#pragma unroll
    for (int i = 0; i < 4; i++)
#pragma unroll
        for (int j = 0; j < 4; j++) {
            acc0[i][j] = (f32x4){0.f, 0.f, 0.f, 0.f};
            acc1[i][j] = (f32x4){0.f, 0.f, 0.f, 0.f};
        }

    int ar = t >> 1, akh = (t & 1) * 16;
    int gr = row0 + ar;
    int nB = col0 + ar;
    const u16* pA  = A  + (size_t)gr * Kp + akh;
    const u16* pB0 = B0 + (size_t)nB * Kp + akh;
    const u16* pB1 = B1 + (size_t)nB * Kp + akh;

    for (int k0 = 0; k0 < Kp; k0 += 32) {
        f16x8 a0{}, a1{};
        if (gr < M) {
            a0 = *(const f16x8*)(pA + k0);
            a1 = *(const f16x8*)(pA + k0 + 8);
        }
        *(f16x8*)&AS[ar][akh]      = a0;
        *(f16x8*)&AS[ar][akh + 8]  = a1;
        *(f16x8*)&B0S[ar][akh]     = *(const f16x8*)(pB0 + k0);
        *(f16x8*)&B0S[ar][akh + 8] = *(const f16x8*)(pB0 + k0 + 8);
        *(f16x8*)&B1S[ar][akh]     = *(const f16x8*)(pB1 + k0);
        *(f16x8*)&B1S[ar][akh + 8] = *(const f16x8*)(pB1 + k0 + 8);
        __syncthreads();

        f16x8 fA[4];
#pragma unroll
        for (int fi = 0; fi < 4; fi++) {
            int r = wr * 64 + fi * 16 + rr;
            fA[fi] = *(const f16x8*)&AS[r][quad * 8];
        }
#pragma unroll
        for (int fj = 0; fj < 4; fj++) {
            int c = wc * 64 + fj * 16 + rr;
            f16x8 b0 = *(const f16x8*)&B0S[c][quad * 8];
            f16x8 b1 = *(const f16x8*)&B1S[c][quad * 8];
#pragma unroll
            for (int fi = 0; fi < 4; fi++) {
                acc0[fi][fj] = __builtin_amdgcn_mfma_f32_16x16x32_f16(fA[fi], b0, acc0[fi][fj], 0, 0, 0);
                acc1[fi][fj] = __builtin_amdgcn_mfma_f32_16x16x32_f16(fA[fi], b1, acc1[fi][fj], 0, 0, 0);
            }
        }
        __syncthreads();
    }

#pragma unroll
    for (int fj = 0; fj < 4; fj++) {
        int gc = col0 + wc * 64 + fj * 16 + rr;
        if (gc >= N) continue;
        float bb0 = bias0 ? bias0[gc] : 0.f;
        float bb1 = bias1 ? bias1[gc] : 0.f;
#pragma unroll
        for (int fi = 0; fi < 4; fi++) {
#pragma unroll
            for (int r = 0; r < 4; r++) {
                int grr = row0 + wr * 64 + fi * 16 + quad * 4 + r;
                if (grr < M) {
                    float v0 = acc0[fi][fj][r] + bb0;
                    float v1 = acc1[fi][fj][r] + bb1;
                    if (fmt & 1) ((u16*)C0v)[(size_t)grr * 256 + gc] = f2h(v0);
                    else         ((float*)C0v)[(size_t)grr * N + gc] = v0;
                    if (fmt & 2) ((u16*)C1v)[(size_t)grr * 256 + gc] = f2h(v1);
                    else         ((float*)C1v)[(size_t)grr * N + gc] = v1;
                }
            }
        }
    }
}

// ---------------- fused edge phase: packed-fp16 single-pass softmax+aggregate ----------------
// 4-edge unroll full-wave; wave-uniform scalarized offsets; output = single fp16
// array [NN][256] (pads zero) = next GEMM's A operand directly.

__global__ __launch_bounds__(256) void fused_edge_kernel(
    const int* __restrict__ rowptr, const int* __restrict__ ssrc,
    const u16* __restrict__ xl16, const float* __restrict__ xr,
    const float* __restrict__ att,
    u16* __restrict__ Oh, int dorelu)
{
    int i = blockIdx.x * 4 + (threadIdx.x >> 6);
    if (i >= NN) return;
    int lane = threadIdx.x & 63;
    int beg = __builtin_amdgcn_readfirstlane(rowptr[i]);
    int end = __builtin_amdgcn_readfirstlane(rowptr[i + 1]);
    int d0 = lane * 4;
    int lb = d0 * 2;                 // lane byte offset into fp16 row

    // masked fp32 loads of xr/att for this lane's 4 dims, converted to fp16 pairs
    float xrf[4] = {0.f, 0.f, 0.f, 0.f};
    float atf[4] = {0.f, 0.f, 0.f, 0.f};
#pragma unroll
    for (int j = 0; j < 4; j++) {
        if (d0 + j < DD) {
            xrf[j] = xr[(size_t)i * DD + d0 + j];
            atf[j] = att[d0 + j];
        }
    }
    h2v xr0h, xr1h, at0h, at1h;
    xr0h.x = (_Float16)xrf[0]; xr0h.y = (_Float16)xrf[1];
    xr1h.x = (_Float16)xrf[2]; xr1h.y = (_Float16)xrf[3];
    at0h.x = (_Float16)atf[0]; at0h.y = (_Float16)atf[1];
    at1h.x = (_Float16)atf[2]; at1h.y = (_Float16)atf[3];
    const h2v c02 = {(_Float16)0.2f, (_Float16)0.2f};

    const char* xlb = (const char*)xl16;

    float m = -1e30f, ssum = 0.f;
    float4 acc = make_float4(0.f, 0.f, 0.f, 0.f);

    int p = beg;
    for (; p + 3 < end; p += 4) {
        int o0 = __builtin_amdgcn_readfirstlane(ssrc[p]);
        int o1 = __builtin_amdgcn_readfirstlane(ssrc[p + 1]);
        int o2 = __builtin_amdgcn_readfirstlane(ssrc[p + 2]);
        int o3 = __builtin_amdgcn_readfirstlane(ssrc[p + 3]);
        uint2 r0 = *(const uint2*)(xlb + o0 + lb);
        uint2 r1 = *(const uint2*)(xlb + o1 + lb);
        uint2 r2 = *(const uint2*)(xlb + o2 + lb);
        uint2 r3 = *(const uint2*)(xlb + o3 + lb);
        h2v x00 = *(h2v*)&r0.x, x01 = *(h2v*)&r0.y;
        h2v x10 = *(h2v*)&r1.x, x11 = *(h2v*)&r1.y;
        h2v x20 = *(h2v*)&r2.x, x21 = *(h2v*)&r2.y;
        h2v x30 = *(h2v*)&r3.x, x31 = *(h2v*)&r3.y;

        h2v s;
        float e0, e1, e2, e3;
        s = x00 + xr0h; s = hmax2v(s, s * c02);
        e0 = __builtin_amdgcn_fdot2(s, at0h, 0.f, false);
        s = x01 + xr1h; s = hmax2v(s, s * c02);
        e0 = __builtin_amdgcn_fdot2(s, at1h, e0, false);
        s = x10 + xr0h; s = hmax2v(s, s * c02);
        e1 = __builtin_amdgcn_fdot2(s, at0h, 0.f, false);
        s = x11 + xr1h; s = hmax2v(s, s * c02);
        e1 = __builtin_amdgcn_fdot2(s, at1h, e1, false);
        s = x20 + xr0h; s = hmax2v(s, s * c02);
        e2 = __builtin_amdgcn_fdot2(s, at0h, 0.f, false);
        s = x21 + xr1h; s = hmax2v(s, s * c02);
        e2 = __builtin_amdgcn_fdot2(s, at1h, e2, false);
        s = x30 + xr0h; s = hmax2v(s, s * c02);
        e3 = __builtin_amdgcn_fdot2(s, at0h, 0.f, false);
        s = x31 + xr1h; s = hmax2v(s, s * c02);
        e3 = __builtin_amdgcn_fdot2(s, at1h, e3, false);

#pragma unroll
        for (int off = 1; off < 64; off <<= 1) {
            e0 += __shfl_xor(e0, off, 64);
            e1 += __shfl_xor(e1, off, 64);
            e2 += __shfl_xor(e2, off, 64);
            e3 += __shfl_xor(e3, off, 64);
        }
        float nm = fmaxf(fmaxf(m, e0), fmaxf(fmaxf(e1, e2), e3));
        float sc = __expf(m - nm);
        float w0 = __expf(e0 - nm);
        float w1 = __expf(e1 - nm);
        float w2 = __expf(e2 - nm);
        float w3 = __expf(e3 - nm);
        // tree-paired accumulate (short dep chains; fma_mix folds the h->f cvt)
        float ax0 = fmaf(w1, (float)x10.x, w0 * (float)x00.x);
        float ax1 = fmaf(w3, (float)x30.x, w2 * (float)x20.x);
        float ay0 = fmaf(w1, (float)x10.y, w0 * (float)x00.y);
        float ay1 = fmaf(w3, (float)x30.y, w2 * (float)x20.y);
        float az0 = fmaf(w1, (float)x11.x, w0 * (float)x01.x);
        float az1 = fmaf(w3, (float)x31.x, w2 * (float)x21.x);
        float aw0 = fmaf(w1, (float)x11.y, w0 * (float)x01.y);
        float aw1 = fmaf(w3, (float)x31.y, w2 * (float)x21.y);
        acc.x = fmaf(acc.x, sc, ax0 + ax1);
        acc.y = fmaf(acc.y, sc, ay0 + ay1);
        acc.z = fmaf(acc.z, sc, az0 + az1);
        acc.w = fmaf(acc.w, sc, aw0 + aw1);
        ssum = fmaf(ssum, sc, (w0 + w1) + (w2 + w3));
        m = nm;
    }
    for (; p < end; p++) {
        int o = __builtin_amdgcn_readfirstlane(ssrc[p]);
        uint2 r = *(const uint2*)(xlb + o + lb);
        h2v x0 = *(h2v*)&r.x, x1 = *(h2v*)&r.y;
        h2v s;
        float e;
        s = x0 + xr0h; s = hmax2v(s, s * c02);
        e = __builtin_amdgcn_fdot2(s, at0h, 0.f, false);
        s = x1 + xr1h; s = hmax2v(s, s * c02);
        e = __builtin_amdgcn_fdot2(s, at1h, e, false);
#pragma unroll
        for (int off = 1; off < 64; off <<= 1)
            e += __shfl_xor(e, off, 64);
        float nm = fmaxf(m, e);
        float sc = __expf(m - nm);
        float w = __expf(e - nm);
        acc.x = fmaf(w, (float)x0.x, acc.x * sc);
        acc.y = fmaf(w, (float)x0.y, acc.y * sc);
        acc.z = fmaf(w, (float)x1.x, acc.z * sc);
        acc.w = fmaf(w, (float)x1.y, acc.w * sc);
        ssum = fmaf(ssum, sc, w);
        m = nm;
    }

    float inv = 1.f / ssum;
    acc.x *= inv; acc.y *= inv; acc.z *= inv; acc.w *= inv;
    if (dorelu) {
        acc.x = fmaxf(acc.x, 0.f); acc.y = fmaxf(acc.y, 0.f);
        acc.z = fmaxf(acc.z, 0.f); acc.w = fmaxf(acc.w, 0.f);
    }
    size_t base = (size_t)i * 256 + d0;
    ushort4 hv;
    hv.x = f2h(acc.x); hv.y = f2h(acc.y); hv.z = f2h(acc.z); hv.w = f2h(acc.w);
    *(ushort4*)&Oh[base] = hv;   // pads (lanes with d0>=DD) write exact zeros
}

// ---------------- query head: 2 queries per wave; fp16 gathers; uniform indices ----------------

__global__ __launch_bounds__(256) void query_kernel(
    const int* __restrict__ qry, const u16* __restrict__ Ptop,
    const u16* __restrict__ Pbot, const float* __restrict__ Wm2,
    const float* __restrict__ bm2, float* __restrict__ out)
{
    int q = (blockIdx.x * 4 + (threadIdx.x >> 6)) * 2;
    if (q >= NQ) return;
    int lane = threadIdx.x & 63;
    int a0 = __builtin_amdgcn_readfirstlane(qry[q * 2 + 0]);
    int b0 = __builtin_amdgcn_readfirstlane(qry[q * 2 + 1]);
    int a1 = __builtin_amdgcn_readfirstlane(qry[q * 2 + 2]);
    int b1 = __builtin_amdgcn_readfirstlane(qry[q * 2 + 3]);
    float4 w  = *(const float4*)&Wm2[lane * 4];
    float4 t0 = ld4h(&Ptop[(size_t)a0 * HD + lane * 4]);
    float4 v0 = ld4h(&Pbot[(size_t)b0 * HD + lane * 4]);
    float4 t1 = ld4h(&Ptop[(size_t)a1 * HD + lane * 4]);
    float4 v1 = ld4h(&Pbot[(size_t)b1 * HD + lane * 4]);
    float s0 = fmaxf(t0.x + v0.x, 0.f) * w.x + fmaxf(t0.y + v0.y, 0.f) * w.y
             + fmaxf(t0.z + v0.z, 0.f) * w.z + fmaxf(t0.w + v0.w, 0.f) * w.w;
    float s1 = fmaxf(t1.x + v1.x, 0.f) * w.x + fmaxf(t1.y + v1.y, 0.f) * w.y
             + fmaxf(t1.z + v1.z, 0.f) * w.z + fmaxf(t1.w + v1.w, 0.f) * w.w;
#pragma unroll
    for (int off = 32; off > 0; off >>= 1) {
        s0 += __shfl_down(s0, off, 64);
        s1 += __shfl_down(s1, off, 64);
    }
    if (lane == 0) {
        float bb = bm2[0];
        out[q] = fmaxf(s0 + bb, 0.f);
        if (q + 1 < NQ) out[q + 1] = fmaxf(s1 + bb, 0.f);
    }
}

// ---------------- launch ----------------

extern "C" void kernel_launch(void* const* d_in, const int* in_sizes, int n_in,
                              void* d_out, int out_size, void* d_ws, size_t ws_size,
                              hipStream_t stream) {
    const float* x    = (const float*)d_in[0];
    const int*   ei   = (const int*)d_in[1];
    const int*   qry  = (const int*)d_in[2];
    const float* W1l  = (const float*)d_in[3];
    const float* b1l  = (const float*)d_in[4];
    const float* W1r  = (const float*)d_in[5];
    const float* b1r  = (const float*)d_in[6];
    const float* att1 = (const float*)d_in[7];
    const float* W2l  = (const float*)d_in[8];
    const float* b2l  = (const float*)d_in[9];
    const float* W2r  = (const float*)d_in[10];
    const float* b2r  = (const float*)d_in[11];
    const float* att2 = (const float*)d_in[12];
    const float* Wm1  = (const float*)d_in[13];
    const float* bm1  = (const float*)d_in[14];
    const float* Wm2  = (const float*)d_in[15];
    const float* bm2  = (const float*)d_in[16];
    float* out = (float*)d_out;

    // workspace carve-up
    const size_t NND = (size_t)NN * DD;          // 12.5M floats
    u16* xl16    = (u16*)d_ws;                   // NN*256 halfs (25.6 MB)
    float* xr    = (float*)(xl16 + (size_t)NN * 256);  // NN*250 floats (50 MB)
    int* rowptr  = (int*)(xr + NND);             // NN+1
    int* fill    = rowptr + NN + 1;              // NN (count buffer)
    int* ssrc    = fill + NN;                    // ET
    int* bsum    = ssrc + ET;                    // 256
    uintptr_t wp = (uintptr_t)(bsum + 256);
    wp = (wp + 63) & ~(uintptr_t)63;
    u16* W1lT = (u16*)wp;                        // 256*128 each
    u16* W1rT = W1lT + 256 * 128;
    u16* W2lT = W1rT + 256 * 128;                // 256*256 each from here
    u16* W2rT = W2lT + 65536;
    u16* WmtT = W2rT + 65536;
    u16* WmbT = WmtT + 65536;
    u16* Asp  = WmbT + 65536;                    // NN*256 fp16 (x [NN][128] early, then h/emb [NN][256])
    // head fp16 buffers overlay xl16 / xr (both dead after layer-2 fused_edge)
    u16* Ptop16 = xl16;                          // NN*256 halfs
    u16* Pbot16 = (u16*)xr;                      // NN*256 halfs

    dim3 blk(256);
    int gET = (ET + 255) / 256;
    int gNode = (NN + 3) / 4;
    int nb = (NN + 255) / 256;                   // 196 scan blocks
    dim3 gg((NN + 127) / 128, 2);

    // ---- conversions + fill zeroing (one dispatch) ----
    conv_all<<<CONVX_BLOCKS + 1280, blk, 0, stream>>>(x, fill, Asp,
        W1l, W1r, W2l, W2r, Wm1,
        W1lT, W1rT, W2lT, W2rT, WmtT, WmbT);

    // ---- CSR build ----
    count_kernel<<<gET, blk, 0, stream>>>(ei, fill);
    scan1_kernel<<<nb, blk, 0, stream>>>(fill, rowptr, bsum);   // also zeroes fill
    scan2_kernel<<<1, blk, 0, stream>>>(bsum, rowptr, nb);
    scan3_kernel<<<nb, blk, 0, stream>>>(rowptr, bsum);
    scatter_kernel<<<gET, blk, 0, stream>>>(ei, rowptr, fill, ssrc);

    // ---- layer 1 (A = x fp16, Kp=128): C0 = xl fp16, C1 = xr fp32 ----
    gemm_pair<<<gg, blk, 0, stream>>>(Asp, 128, W1lT, W1rT,
                                      b1l, b1r, (void*)xl16, (void*)xr, NN, DD, 1);
    fused_edge_kernel<<<gNode, blk, 0, stream>>>(rowptr, ssrc, xl16, xr, att1, Asp, 1);

    // ---- layer 2 (A = h fp16, Kp=256) ----
    gemm_pair<<<gg, blk, 0, stream>>>(Asp, 256, W2lT, W2rT,
                                      b2l, b2r, (void*)xl16, (void*)xr, NN, DD, 1);
    fused_edge_kernel<<<gNode, blk, 0, stream>>>(rowptr, ssrc, xl16, xr, att2, Asp, 0);

    // ---- head precompute (A = emb fp16, Kp=256): both outputs fp16 ----
    gemm_pair<<<gg, blk, 0, stream>>>(Asp, 256, WmtT, WmbT,
                                      bm1, (const float*)nullptr, (void*)Ptop16, (void*)Pbot16, NN, HD, 3);

    // ---- per-query head ----
    query_kernel<<<(NQ / 2 + 3) / 4, blk, 0, stream>>>(qry, Ptop16, Pbot16, Wm2, bm2, out);
}

// Round 21
// 528.883 us; speedup vs baseline: 1.1569x; 1.0235x over previous
//
#include <hip/hip_runtime.h>
#include <hip/hip_fp16.h>
#include <math.h>
#include <stdint.h>

#define NN 50000
#define NE 800000
#define ET (NE + NN)      // 850000 edges incl self loops
#define FIN 128
#define DD 250
#define HD 256
#define NQ 200000
#define NEG_SLOPE 0.2f

typedef unsigned short u16;
typedef __attribute__((ext_vector_type(4))) float f32x4;
typedef _Float16 h2v __attribute__((ext_vector_type(2)));
typedef _Float16 f16x8 __attribute__((ext_vector_type(8)));

__device__ __forceinline__ u16 f2h(float v) {
    __half h = __float2half(v);
    return *reinterpret_cast<u16*>(&h);
}
// load 4 fp16 (8B) -> float4 (used by query kernel)
__device__ __forceinline__ float4 ld4h(const u16* p) {
    uint2 r = *(const uint2*)p;
    __half2 a = *(__half2*)&r.x;
    __half2 b = *(__half2*)&r.y;
    float2 fa = __half22float2(a), fb = __half22float2(b);
    return make_float4(fa.x, fa.y, fb.x, fb.y);
}
// packed fp16 max -> v_pk_max_f16 (avoids ROCm __hmax2 header overload issues)
__device__ __forceinline__ h2v hmax2v(h2v a, h2v b) {
    return __builtin_elementwise_max(a, b);
}

// ---------------- CSR build ----------------

__global__ void count_kernel(const int* __restrict__ ei, int* __restrict__ cnt) {
    int k = blockIdx.x * 256 + threadIdx.x;
    if (k >= ET) return;
    int d = (k < NE) ? ei[NE + k] : (k - NE);
    atomicAdd(&cnt[d], 1);
}

__global__ __launch_bounds__(256) void scan1_kernel(
    int* __restrict__ cnt, int* __restrict__ rowptr, int* __restrict__ bsum)
{
    __shared__ int buf[256];
    int t = threadIdx.x;
    int i = blockIdx.x * 256 + t;
    int v = (i < NN) ? cnt[i] : 0;
    if (i < NN) cnt[i] = 0;          // zero fill for scatter
    buf[t] = v;
    __syncthreads();
#pragma unroll
    for (int off = 1; off < 256; off <<= 1) {
        int add = (t >= off) ? buf[t - off] : 0;
        __syncthreads();
        buf[t] += add;
        __syncthreads();
    }
    if (i < NN) rowptr[i] = buf[t] - v;     // block-local exclusive
    if (t == 255) bsum[blockIdx.x] = buf[255];
}

__global__ __launch_bounds__(256) void scan2_kernel(
    int* __restrict__ bsum, int* __restrict__ rowptr, int nb)
{
    __shared__ int buf[256];
    int t = threadIdx.x;
    int v = (t < nb) ? bsum[t] : 0;
    buf[t] = v;
    __syncthreads();
#pragma unroll
    for (int off = 1; off < 256; off <<= 1) {
        int add = (t >= off) ? buf[t - off] : 0;
        __syncthreads();
        buf[t] += add;
        __syncthreads();
    }
    if (t < nb) bsum[t] = buf[t] - v;
    if (t == 255) rowptr[NN] = buf[255];
}

__global__ __launch_bounds__(256) void scan3_kernel(
    int* __restrict__ rowptr, const int* __restrict__ bsum)
{
    int i = blockIdx.x * 256 + threadIdx.x;
    if (i < NN) rowptr[i] += bsum[blockIdx.x];
}

// stores premultiplied src BYTE offset (s*512, fp16-row stride) for the fused kernel
__global__ void scatter_kernel(const int* __restrict__ ei,
                               const int* __restrict__ rowptr,
                               int* __restrict__ fill,
                               int* __restrict__ ssrc) {
    int k = blockIdx.x * 256 + threadIdx.x;
    if (k >= ET) return;
    int s, d;
    if (k < NE) { s = ei[k]; d = ei[NE + k]; }
    else        { s = k - NE; d = k - NE; }
    int pos = rowptr[d] + atomicAdd(&fill[d], 1);
    ssrc[pos] = s << 9;
}

// ---------------- combined conversion kernel (all fp16 now) ----------------

#define CONVX_BLOCKS 3125

__global__ __launch_bounds__(256) void conv_all(
    const float* __restrict__ x, int* __restrict__ fill,
    u16* __restrict__ Asp,
    const float* __restrict__ W1l, const float* __restrict__ W1r,
    const float* __restrict__ W2l, const float* __restrict__ W2r,
    const float* __restrict__ Wm1,
    u16* __restrict__ W1lT, u16* __restrict__ W1rT,
    u16* __restrict__ W2lT, u16* __restrict__ W2rT,
    u16* __restrict__ WmtT, u16* __restrict__ WmbT)
{
    if (blockIdx.x < CONVX_BLOCKS) {
        int tid = blockIdx.x * 256 + threadIdx.x;
        if (tid < NN) fill[tid] = 0;
        size_t idx = (size_t)tid * 8;
        if (idx >= (size_t)NN * FIN) return;
        float4 v0 = *(const float4*)(x + idx);
        float4 v1 = *(const float4*)(x + idx + 4);
        ushort4 o0, o1;
        o0.x = f2h(v0.x); o0.y = f2h(v0.y); o0.z = f2h(v0.z); o0.w = f2h(v0.w);
        o1.x = f2h(v1.x); o1.y = f2h(v1.y); o1.z = f2h(v1.z); o1.w = f2h(v1.w);
        *(ushort4*)(Asp + idx) = o0;
        *(ushort4*)(Asp + idx + 4) = o1;
        return;
    }
    int b = blockIdx.x - CONVX_BLOCKS;
    const float* W; int K, N, koff, kshift, b0; u16* ot;
    if (b < 128)       { W = W1l; K = FIN; N = DD; koff = 0;  kshift = 7; b0 = 0;    ot = W1lT; }
    else if (b < 256)  { W = W1r; K = FIN; N = DD; koff = 0;  kshift = 7; b0 = 128;  ot = W1rT; }
    else if (b < 512)  { W = W2l; K = DD;  N = DD; koff = 0;  kshift = 8; b0 = 256;  ot = W2lT; }
    else if (b < 768)  { W = W2r; K = DD;  N = DD; koff = 0;  kshift = 8; b0 = 512;  ot = W2rT; }
    else if (b < 1024) { W = Wm1; K = DD;  N = HD; koff = 0;  kshift = 8; b0 = 768;  ot = WmtT; }
    else               { W = Wm1; K = DD;  N = HD; koff = DD; kshift = 8; b0 = 1024; ot = WmbT; }
    int id = (b - b0) * 256 + threadIdx.x;
    int Kp = 1 << kshift;
    int n = id >> kshift, k = id & (Kp - 1);
    float v = (n < N && k < K) ? W[(size_t)(k + koff) * N + n] : 0.f;
    ot[id] = f2h(v);
}

// ---------------- fp16 MFMA pair-GEMM ----------------
// Pure fp16 operands (fp32 accumulate). All outputs fp16 stride-256 except the
// fmt=0 fp32 path (unused now, kept for flexibility).
// fmt bit0: C0 as fp16 stride-256; bit1: C1 as fp16 stride-256; else fp32 stride-N

#define AP 40   // padded LDS row length (u16)

__global__ __launch_bounds__(256, 2) void gemm_pair(
    const u16* __restrict__ A, int Kp,
    const u16* __restrict__ B0, const u16* __restrict__ B1,
    const float* __restrict__ bias0, const float* __restrict__ bias1,
    void* __restrict__ C0v, void* __restrict__ C1v, int M, int N, int fmt)
{
    __shared__ u16 AS[128][AP], B0S[128][AP], B1S[128][AP];

    int row0 = blockIdx.x * 128;
    int col0 = blockIdx.y * 128;
    int t = threadIdx.x;
    int lane = t & 63, w = t >> 6;
    int wr = w >> 1, wc = w & 1;
    int quad = lane >> 4, rr = lane & 15;

    f32x4 acc0[4][4], acc1[4][4];
#pragma unroll
    for (int i = 0; i < 4; i++)
#pragma unroll
        for (int j = 0; j < 4; j++) {
            acc0[i][j] = (f32x4){0.f, 0.f, 0.f, 0.f};
            acc1[i][j] = (f32x4){0.f, 0.f, 0.f, 0.f};
        }

    int ar = t >> 1, akh = (t & 1) * 16;
    int gr = row0 + ar;
    int nB = col0 + ar;
    const u16* pA  = A  + (size_t)gr * Kp + akh;
    const u16* pB0 = B0 + (size_t)nB * Kp + akh;
    const u16* pB1 = B1 + (size_t)nB * Kp + akh;

    for (int k0 = 0; k0 < Kp; k0 += 32) {
        f16x8 a0{}, a1{};
        if (gr < M) {
            a0 = *(const f16x8*)(pA + k0);
            a1 = *(const f16x8*)(pA + k0 + 8);
        }
        *(f16x8*)&AS[ar][akh]      = a0;
        *(f16x8*)&AS[ar][akh + 8]  = a1;
        *(f16x8*)&B0S[ar][akh]     = *(const f16x8*)(pB0 + k0);
        *(f16x8*)&B0S[ar][akh + 8] = *(const f16x8*)(pB0 + k0 + 8);
        *(f16x8*)&B1S[ar][akh]     = *(const f16x8*)(pB1 + k0);
        *(f16x8*)&B1S[ar][akh + 8] = *(const f16x8*)(pB1 + k0 + 8);
        __syncthreads();

        f16x8 fA[4];
#pragma unroll
        for (int fi = 0; fi < 4; fi++) {
            int r = wr * 64 + fi * 16 + rr;
            fA[fi] = *(const f16x8*)&AS[r][quad * 8];
        }
#pragma unroll
        for (int fj = 0; fj < 4; fj++) {
            int c = wc * 64 + fj * 16 + rr;
            f16x8 b0 = *(const f16x8*)&B0S[c][quad * 8];
            f16x8 b1 = *(const f16x8*)&B1S[c][quad * 8];
#pragma unroll
            for (int fi = 0; fi < 4; fi++) {
                acc0[fi][fj] = __builtin_amdgcn_mfma_f32_16x16x32_f16(fA[fi], b0, acc0[fi][fj], 0, 0, 0);
                acc1[fi][fj] = __builtin_amdgcn_mfma_f32_16x16x32_f16(fA[fi], b1, acc1[fi][fj], 0, 0, 0);
            }
        }
        __syncthreads();
    }

#pragma unroll
    for (int fj = 0; fj < 4; fj++) {
        int gc = col0 + wc * 64 + fj * 16 + rr;
        if (gc >= N) continue;
        float bb0 = bias0 ? bias0[gc] : 0.f;
        float bb1 = bias1 ? bias1[gc] : 0.f;
#pragma unroll
        for (int fi = 0; fi < 4; fi++) {
#pragma unroll
            for (int r = 0; r < 4; r++) {
                int grr = row0 + wr * 64 + fi * 16 + quad * 4 + r;
                if (grr < M) {
                    float v0 = acc0[fi][fj][r] + bb0;
                    float v1 = acc1[fi][fj][r] + bb1;
                    if (fmt & 1) ((u16*)C0v)[(size_t)grr * 256 + gc] = f2h(v0);
                    else         ((float*)C0v)[(size_t)grr * N + gc] = v0;
                    if (fmt & 2) ((u16*)C1v)[(size_t)grr * 256 + gc] = f2h(v1);
                    else         ((float*)C1v)[(size_t)grr * N + gc] = v1;
                }
            }
        }
    }
}

// ---------------- fused edge phase: packed-fp16 single-pass softmax+aggregate ----------------
// 4-edge unroll full-wave; wave-uniform scalarized offsets; xl AND xr both fp16
// stride-256 (xr fp16 is bit-identical to the previous fp32-load+cvt since the
// same f2h conversion now happens in the GEMM epilogue). att pads are zeroed, so
// xl/xr pad garbage (d>=250) is annihilated in the dot.

__global__ __launch_bounds__(256) void fused_edge_kernel(
    const int* __restrict__ rowptr, const int* __restrict__ ssrc,
    const u16* __restrict__ xl16, const u16* __restrict__ xr16,
    const float* __restrict__ att,
    u16* __restrict__ Oh, int dorelu)
{
    int i = blockIdx.x * 4 + (threadIdx.x >> 6);
    if (i >= NN) return;
    int lane = threadIdx.x & 63;
    int beg = __builtin_amdgcn_readfirstlane(rowptr[i]);
    int end = __builtin_amdgcn_readfirstlane(rowptr[i + 1]);
    int d0 = lane * 4;
    int lb = d0 * 2;                 // lane byte offset into fp16 row

    // xr chunk: direct fp16 load (pads garbage but killed by zero att)
    uint2 xrr = *(const uint2*)&xr16[(size_t)i * 256 + d0];
    h2v xr0h = *(h2v*)&xrr.x, xr1h = *(h2v*)&xrr.y;
    // att: masked fp32 loads -> fp16 (pads exact zero)
    float atf[4] = {0.f, 0.f, 0.f, 0.f};
#pragma unroll
    for (int j = 0; j < 4; j++)
        if (d0 + j < DD) atf[j] = att[d0 + j];
    h2v at0h, at1h;
    at0h.x = (_Float16)atf[0]; at0h.y = (_Float16)atf[1];
    at1h.x = (_Float16)atf[2]; at1h.y = (_Float16)atf[3];
    const h2v c02 = {(_Float16)0.2f, (_Float16)0.2f};

    const char* xlb = (const char*)xl16;

    float m = -1e30f, ssum = 0.f;
    float4 acc = make_float4(0.f, 0.f, 0.f, 0.f);

    int p = beg;
    for (; p + 3 < end; p += 4) {
        int o0 = __builtin_amdgcn_readfirstlane(ssrc[p]);
        int o1 = __builtin_amdgcn_readfirstlane(ssrc[p + 1]);
        int o2 = __builtin_amdgcn_readfirstlane(ssrc[p + 2]);
        int o3 = __builtin_amdgcn_readfirstlane(ssrc[p + 3]);
        uint2 r0 = *(const uint2*)(xlb + o0 + lb);
        uint2 r1 = *(const uint2*)(xlb + o1 + lb);
        uint2 r2 = *(const uint2*)(xlb + o2 + lb);
        uint2 r3 = *(const uint2*)(xlb + o3 + lb);
        h2v x00 = *(h2v*)&r0.x, x01 = *(h2v*)&r0.y;
        h2v x10 = *(h2v*)&r1.x, x11 = *(h2v*)&r1.y;
        h2v x20 = *(h2v*)&r2.x, x21 = *(h2v*)&r2.y;
        h2v x30 = *(h2v*)&r3.x, x31 = *(h2v*)&r3.y;

        h2v s;
        float e0, e1, e2, e3;
        s = x00 + xr0h; s = hmax2v(s, s * c02);
        e0 = __builtin_amdgcn_fdot2(s, at0h, 0.f, false);
        s = x01 + xr1h; s = hmax2v(s, s * c02);
        e0 = __builtin_amdgcn_fdot2(s, at1h, e0, false);
        s = x10 + xr0h; s = hmax2v(s, s * c02);
        e1 = __builtin_amdgcn_fdot2(s, at0h, 0.f, false);
        s = x11 + xr1h; s = hmax2v(s, s * c02);
        e1 = __builtin_amdgcn_fdot2(s, at1h, e1, false);
        s = x20 + xr0h; s = hmax2v(s, s * c02);
        e2 = __builtin_amdgcn_fdot2(s, at0h, 0.f, false);
        s = x21 + xr1h; s = hmax2v(s, s * c02);
        e2 = __builtin_amdgcn_fdot2(s, at1h, e2, false);
        s = x30 + xr0h; s = hmax2v(s, s * c02);
        e3 = __builtin_amdgcn_fdot2(s, at0h, 0.f, false);
        s = x31 + xr1h; s = hmax2v(s, s * c02);
        e3 = __builtin_amdgcn_fdot2(s, at1h, e3, false);

#pragma unroll
        for (int off = 1; off < 64; off <<= 1) {
            e0 += __shfl_xor(e0, off, 64);
            e1 += __shfl_xor(e1, off, 64);
            e2 += __shfl_xor(e2, off, 64);
            e3 += __shfl_xor(e3, off, 64);
        }
        float nm = fmaxf(fmaxf(m, e0), fmaxf(fmaxf(e1, e2), e3));
        float sc = __expf(m - nm);
        float w0 = __expf(e0 - nm);
        float w1 = __expf(e1 - nm);
        float w2 = __expf(e2 - nm);
        float w3 = __expf(e3 - nm);
        // tree-paired accumulate (short dep chains; fma_mix folds the h->f cvt)
        float ax0 = fmaf(w1, (float)x10.x, w0 * (float)x00.x);
        float ax1 = fmaf(w3, (float)x30.x, w2 * (float)x20.x);
        float ay0 = fmaf(w1, (float)x10.y, w0 * (float)x00.y);
        float ay1 = fmaf(w3, (float)x30.y, w2 * (float)x20.y);
        float az0 = fmaf(w1, (float)x11.x, w0 * (float)x01.x);
        float az1 = fmaf(w3, (float)x31.x, w2 * (float)x21.x);
        float aw0 = fmaf(w1, (float)x11.y, w0 * (float)x01.y);
        float aw1 = fmaf(w3, (float)x31.y, w2 * (float)x21.y);
        acc.x = fmaf(acc.x, sc, ax0 + ax1);
        acc.y = fmaf(acc.y, sc, ay0 + ay1);
        acc.z = fmaf(acc.z, sc, az0 + az1);
        acc.w = fmaf(acc.w, sc, aw0 + aw1);
        ssum = fmaf(ssum, sc, (w0 + w1) + (w2 + w3));
        m = nm;
    }
    for (; p < end; p++) {
        int o = __builtin_amdgcn_readfirstlane(ssrc[p]);
        uint2 r = *(const uint2*)(xlb + o + lb);
        h2v x0 = *(h2v*)&r.x, x1 = *(h2v*)&r.y;
        h2v s;
        float e;
        s = x0 + xr0h; s = hmax2v(s, s * c02);
        e = __builtin_amdgcn_fdot2(s, at0h, 0.f, false);
        s = x1 + xr1h; s = hmax2v(s, s * c02);
        e = __builtin_amdgcn_fdot2(s, at1h, e, false);
#pragma unroll
        for (int off = 1; off < 64; off <<= 1)
            e += __shfl_xor(e, off, 64);
        float nm = fmaxf(m, e);
        float sc = __expf(m - nm);
        float w = __expf(e - nm);
        acc.x = fmaf(w, (float)x0.x, acc.x * sc);
        acc.y = fmaf(w, (float)x0.y, acc.y * sc);
        acc.z = fmaf(w, (float)x1.x, acc.z * sc);
        acc.w = fmaf(w, (float)x1.y, acc.w * sc);
        ssum = fmaf(ssum, sc, w);
        m = nm;
    }

    float inv = 1.f / ssum;
    acc.x *= inv; acc.y *= inv; acc.z *= inv; acc.w *= inv;
    if (dorelu) {
        acc.x = fmaxf(acc.x, 0.f); acc.y = fmaxf(acc.y, 0.f);
        acc.z = fmaxf(acc.z, 0.f); acc.w = fmaxf(acc.w, 0.f);
    }
    size_t base = (size_t)i * 256 + d0;
    ushort4 hv;
    hv.x = f2h(acc.x); hv.y = f2h(acc.y); hv.z = f2h(acc.z); hv.w = f2h(acc.w);
    *(ushort4*)&Oh[base] = hv;   // pad lanes write their (harmless) values; B k-pads are zero
}

// ---------------- query head: 2 queries per wave; fp16 gathers; uniform indices ----------------

__global__ __launch_bounds__(256) void query_kernel(
    const int* __restrict__ qry, const u16* __restrict__ Ptop,
    const u16* __restrict__ Pbot, const float* __restrict__ Wm2,
    const float* __restrict__ bm2, float* __restrict__ out)
{
    int q = (blockIdx.x * 4 + (threadIdx.x >> 6)) * 2;
    if (q >= NQ) return;
    int lane = threadIdx.x & 63;
    int a0 = __builtin_amdgcn_readfirstlane(qry[q * 2 + 0]);
    int b0 = __builtin_amdgcn_readfirstlane(qry[q * 2 + 1]);
    int a1 = __builtin_amdgcn_readfirstlane(qry[q * 2 + 2]);
    int b1 = __builtin_amdgcn_readfirstlane(qry[q * 2 + 3]);
    float4 w  = *(const float4*)&Wm2[lane * 4];
    float4 t0 = ld4h(&Ptop[(size_t)a0 * HD + lane * 4]);
    float4 v0 = ld4h(&Pbot[(size_t)b0 * HD + lane * 4]);
    float4 t1 = ld4h(&Ptop[(size_t)a1 * HD + lane * 4]);
    float4 v1 = ld4h(&Pbot[(size_t)b1 * HD + lane * 4]);
    float s0 = fmaxf(t0.x + v0.x, 0.f) * w.x + fmaxf(t0.y + v0.y, 0.f) * w.y
             + fmaxf(t0.z + v0.z, 0.f) * w.z + fmaxf(t0.w + v0.w, 0.f) * w.w;
    float s1 = fmaxf(t1.x + v1.x, 0.f) * w.x + fmaxf(t1.y + v1.y, 0.f) * w.y
             + fmaxf(t1.z + v1.z, 0.f) * w.z + fmaxf(t1.w + v1.w, 0.f) * w.w;
#pragma unroll
    for (int off = 32; off > 0; off >>= 1) {
        s0 += __shfl_down(s0, off, 64);
        s1 += __shfl_down(s1, off, 64);
    }
    if (lane == 0) {
        float bb = bm2[0];
        out[q] = fmaxf(s0 + bb, 0.f);
        if (q + 1 < NQ) out[q + 1] = fmaxf(s1 + bb, 0.f);
    }
}

// ---------------- launch ----------------

extern "C" void kernel_launch(void* const* d_in, const int* in_sizes, int n_in,
                              void* d_out, int out_size, void* d_ws, size_t ws_size,
                              hipStream_t stream) {
    const float* x    = (const float*)d_in[0];
    const int*   ei   = (const int*)d_in[1];
    const int*   qry  = (const int*)d_in[2];
    const float* W1l  = (const float*)d_in[3];
    const float* b1l  = (const float*)d_in[4];
    const float* W1r  = (const float*)d_in[5];
    const float* b1r  = (const float*)d_in[6];
    const float* att1 = (const float*)d_in[7];
    const float* W2l  = (const float*)d_in[8];
    const float* b2l  = (const float*)d_in[9];
    const float* W2r  = (const float*)d_in[10];
    const float* b2r  = (const float*)d_in[11];
    const float* att2 = (const float*)d_in[12];
    const float* Wm1  = (const float*)d_in[13];
    const float* bm1  = (const float*)d_in[14];
    const float* Wm2  = (const float*)d_in[15];
    const float* bm2  = (const float*)d_in[16];
    float* out = (float*)d_out;

    // workspace carve-up (all node tensors fp16 stride-256 now)
    u16* xl16    = (u16*)d_ws;                   // NN*256 halfs (25.6 MB)
    u16* xr16    = xl16 + (size_t)NN * 256;      // NN*256 halfs (25.6 MB)
    int* rowptr  = (int*)(xr16 + (size_t)NN * 256);  // NN+1
    int* fill    = rowptr + NN + 1;              // NN (count buffer)
    int* ssrc    = fill + NN;                    // ET
    int* bsum    = ssrc + ET;                    // 256
    uintptr_t wp = (uintptr_t)(bsum + 256);
    wp = (wp + 63) & ~(uintptr_t)63;
    u16* W1lT = (u16*)wp;                        // 256*128 each
    u16* W1rT = W1lT + 256 * 128;
    u16* W2lT = W1rT + 256 * 128;                // 256*256 each from here
    u16* W2rT = W2lT + 65536;
    u16* WmtT = W2rT + 65536;
    u16* WmbT = WmtT + 65536;
    u16* Asp  = WmbT + 65536;                    // NN*256 fp16 (x [NN][128] early, then h/emb [NN][256])
    // head fp16 buffers overlay xl16 / xr16 (both dead after layer-2 fused_edge)
    u16* Ptop16 = xl16;                          // NN*256 halfs
    u16* Pbot16 = xr16;                          // NN*256 halfs

    dim3 blk(256);
    int gET = (ET + 255) / 256;
    int gNode = (NN + 3) / 4;
    int nb = (NN + 255) / 256;                   // 196 scan blocks
    dim3 gg((NN + 127) / 128, 2);

    // ---- conversions + fill zeroing (one dispatch) ----
    conv_all<<<CONVX_BLOCKS + 1280, blk, 0, stream>>>(x, fill, Asp,
        W1l, W1r, W2l, W2r, Wm1,
        W1lT, W1rT, W2lT, W2rT, WmtT, WmbT);

    // ---- CSR build ----
    count_kernel<<<gET, blk, 0, stream>>>(ei, fill);
    scan1_kernel<<<nb, blk, 0, stream>>>(fill, rowptr, bsum);   // also zeroes fill
    scan2_kernel<<<1, blk, 0, stream>>>(bsum, rowptr, nb);
    scan3_kernel<<<nb, blk, 0, stream>>>(rowptr, bsum);
    scatter_kernel<<<gET, blk, 0, stream>>>(ei, rowptr, fill, ssrc);

    // ---- layer 1 (A = x fp16, Kp=128): both outputs fp16 stride-256 ----
    gemm_pair<<<gg, blk, 0, stream>>>(Asp, 128, W1lT, W1rT,
                                      b1l, b1r, (void*)xl16, (void*)xr16, NN, DD, 3);
    fused_edge_kernel<<<gNode, blk, 0, stream>>>(rowptr, ssrc, xl16, xr16, att1, Asp, 1);

    // ---- layer 2 (A = h fp16, Kp=256) ----
    gemm_pair<<<gg, blk, 0, stream>>>(Asp, 256, W2lT, W2rT,
                                      b2l, b2r, (void*)xl16, (void*)xr16, NN, DD, 3);
    fused_edge_kernel<<<gNode, blk, 0, stream>>>(rowptr, ssrc, xl16, xr16, att2, Asp, 0);

    // ---- head precompute (A = emb fp16, Kp=256): both outputs fp16 ----
    gemm_pair<<<gg, blk, 0, stream>>>(Asp, 256, WmtT, WmbT,
                                      bm1, (const float*)nullptr, (void*)Ptop16, (void*)Pbot16, NN, HD, 3);

    // ---- per-query head ----
    query_kernel<<<(NQ / 2 + 3) / 4, blk, 0, stream>>>(qry, Ptop16, Pbot16, Wm2, bm2, out);
}

// Round 22
// 526.346 us; speedup vs baseline: 1.1624x; 1.0048x over previous
//
#include <hip/hip_runtime.h>
#include <hip/hip_fp16.h>
#include <math.h>
#include <stdint.h>

#define NN 50000
#define NE 800000
#define ET (NE + NN)      // 850000 edges incl self loops
#define FIN 128
#define DD 250
#define HD 256
#define NQ 200000
#define NEG_SLOPE 0.2f

typedef unsigned short u16;
typedef __attribute__((ext_vector_type(4))) float f32x4;
typedef _Float16 h2v __attribute__((ext_vector_type(2)));
typedef _Float16 f16x8 __attribute__((ext_vector_type(8)));

union H2U { h2v h; unsigned int u; };

__device__ __forceinline__ u16 f2h(float v) {
    __half h = __float2half(v);
    return *reinterpret_cast<u16*>(&h);
}
// load 4 fp16 (8B) -> float4 (used by query kernel)
__device__ __forceinline__ float4 ld4h(const u16* p) {
    uint2 r = *(const uint2*)p;
    __half2 a = *(__half2*)&r.x;
    __half2 b = *(__half2*)&r.y;
    float2 fa = __half22float2(a), fb = __half22float2(b);
    return make_float4(fa.x, fa.y, fb.x, fb.y);
}
// packed fp16 max -> v_pk_max_f16 (avoids ROCm __hmax2 header overload issues)
__device__ __forceinline__ h2v hmax2v(h2v a, h2v b) {
    return __builtin_elementwise_max(a, b);
}

// ---------------- CSR build ----------------

__global__ void count_kernel(const int* __restrict__ ei, int* __restrict__ cnt) {
    int k = blockIdx.x * 256 + threadIdx.x;
    if (k >= ET) return;
    int d = (k < NE) ? ei[NE + k] : (k - NE);
    atomicAdd(&cnt[d], 1);
}

__global__ __launch_bounds__(256) void scan1_kernel(
    int* __restrict__ cnt, int* __restrict__ rowptr, int* __restrict__ bsum)
{
    __shared__ int buf[256];
    int t = threadIdx.x;
    int i = blockIdx.x * 256 + t;
    int v = (i < NN) ? cnt[i] : 0;
    if (i < NN) cnt[i] = 0;          // zero fill for scatter
    buf[t] = v;
    __syncthreads();
#pragma unroll
    for (int off = 1; off < 256; off <<= 1) {
        int add = (t >= off) ? buf[t - off] : 0;
        __syncthreads();
        buf[t] += add;
        __syncthreads();
    }
    if (i < NN) rowptr[i] = buf[t] - v;     // block-local exclusive
    if (t == 255) bsum[blockIdx.x] = buf[255];
}

__global__ __launch_bounds__(256) void scan2_kernel(
    int* __restrict__ bsum, int* __restrict__ rowptr, int nb)
{
    __shared__ int buf[256];
    int t = threadIdx.x;
    int v = (t < nb) ? bsum[t] : 0;
    buf[t] = v;
    __syncthreads();
#pragma unroll
    for (int off = 1; off < 256; off <<= 1) {
        int add = (t >= off) ? buf[t - off] : 0;
        __syncthreads();
        buf[t] += add;
        __syncthreads();
    }
    if (t < nb) bsum[t] = buf[t] - v;
    if (t == 255) rowptr[NN] = buf[255];
}

__global__ __launch_bounds__(256) void scan3_kernel(
    int* __restrict__ rowptr, const int* __restrict__ bsum)
{
    int i = blockIdx.x * 256 + threadIdx.x;
    if (i < NN) rowptr[i] += bsum[blockIdx.x];
}

// stores premultiplied src BYTE offset (s*512, fp16-row stride) for the fused kernel
__global__ void scatter_kernel(const int* __restrict__ ei,
                               const int* __restrict__ rowptr,
                               int* __restrict__ fill,
                               int* __restrict__ ssrc) {
    int k = blockIdx.x * 256 + threadIdx.x;
    if (k >= ET) return;
    int s, d;
    if (k < NE) { s = ei[k]; d = ei[NE + k]; }
    else        { s = k - NE; d = k - NE; }
    int pos = rowptr[d] + atomicAdd(&fill[d], 1);
    ssrc[pos] = s << 9;
}

// ---------------- combined conversion kernel (all fp16 now) ----------------

#define CONVX_BLOCKS 3125

__global__ __launch_bounds__(256) void conv_all(
    const float* __restrict__ x, int* __restrict__ fill,
    u16* __restrict__ Asp,
    const float* __restrict__ W1l, const float* __restrict__ W1r,
    const float* __restrict__ W2l, const float* __restrict__ W2r,
    const float* __restrict__ Wm1,
    u16* __restrict__ W1lT, u16* __restrict__ W1rT,
    u16* __restrict__ W2lT, u16* __restrict__ W2rT,
    u16* __restrict__ WmtT, u16* __restrict__ WmbT)
{
    if (blockIdx.x < CONVX_BLOCKS) {
        int tid = blockIdx.x * 256 + threadIdx.x;
        if (tid < NN) fill[tid] = 0;
        size_t idx = (size_t)tid * 8;
        if (idx >= (size_t)NN * FIN) return;
        float4 v0 = *(const float4*)(x + idx);
        float4 v1 = *(const float4*)(x + idx + 4);
        ushort4 o0, o1;
        o0.x = f2h(v0.x); o0.y = f2h(v0.y); o0.z = f2h(v0.z); o0.w = f2h(v0.w);
        o1.x = f2h(v1.x); o1.y = f2h(v1.y); o1.z = f2h(v1.z); o1.w = f2h(v1.w);
        *(ushort4*)(Asp + idx) = o0;
        *(ushort4*)(Asp + idx + 4) = o1;
        return;
    }
    int b = blockIdx.x - CONVX_BLOCKS;
    const float* W; int K, N, koff, kshift, b0; u16* ot;
    if (b < 128)       { W = W1l; K = FIN; N = DD; koff = 0;  kshift = 7; b0 = 0;    ot = W1lT; }
    else if (b < 256)  { W = W1r; K = FIN; N = DD; koff = 0;  kshift = 7; b0 = 128;  ot = W1rT; }
    else if (b < 512)  { W = W2l; K = DD;  N = DD; koff = 0;  kshift = 8; b0 = 256;  ot = W2lT; }
    else if (b < 768)  { W = W2r; K = DD;  N = DD; koff = 0;  kshift = 8; b0 = 512;  ot = W2rT; }
    else if (b < 1024) { W = Wm1; K = DD;  N = HD; koff = 0;  kshift = 8; b0 = 768;  ot = WmtT; }
    else               { W = Wm1; K = DD;  N = HD; koff = DD; kshift = 8; b0 = 1024; ot = WmbT; }
    int id = (b - b0) * 256 + threadIdx.x;
    int Kp = 1 << kshift;
    int n = id >> kshift, k = id & (Kp - 1);
    float v = (n < N && k < K) ? W[(size_t)(k + koff) * N + n] : 0.f;
    ot[id] = f2h(v);
}

// ---------------- fp16 MFMA pair-GEMM ----------------
// Pure fp16 operands (fp32 accumulate).
// fmt bit0: C0 as fp16 stride-256; bit1: C1 as fp16 stride-256; else fp32 stride-N

#define AP 40   // padded LDS row length (u16)

__global__ __launch_bounds__(256, 2) void gemm_pair(
    const u16* __restrict__ A, int Kp,
    const u16* __restrict__ B0, const u16* __restrict__ B1,
    const float* __restrict__ bias0, const float* __restrict__ bias1,
    void* __restrict__ C0v, void* __restrict__ C1v, int M, int N, int fmt)
{
    __shared__ u16 AS[128][AP], B0S[128][AP], B1S[128][AP];

    int row0 = blockIdx.x * 128;
    int col0 = blockIdx.y * 128;
    int t = threadIdx.x;
    int lane = t & 63, w = t >> 6;
    int wr = w >> 1, wc = w & 1;
    int quad = lane >> 4, rr = lane & 15;

    f32x4 acc0[4][4], acc1[4][4];
#pragma unroll
    for (int i = 0; i < 4; i++)
#pragma unroll
        for (int j = 0; j < 4; j++) {
            acc0[i][j] = (f32x4){0.f, 0.f, 0.f, 0.f};
            acc1[i][j] = (f32x4){0.f, 0.f, 0.f, 0.f};
        }

    int ar = t >> 1, akh = (t & 1) * 16;
    int gr = row0 + ar;
    int nB = col0 + ar;
    const u16* pA  = A  + (size_t)gr * Kp + akh;
    const u16* pB0 = B0 + (size_t)nB * Kp + akh;
    const u16* pB1 = B1 + (size_t)nB * Kp + akh;

    for (int k0 = 0; k0 < Kp; k0 += 32) {
        f16x8 a0{}, a1{};
        if (gr < M) {
            a0 = *(const f16x8*)(pA + k0);
            a1 = *(const f16x8*)(pA + k0 + 8);
        }
        *(f16x8*)&AS[ar][akh]      = a0;
        *(f16x8*)&AS[ar][akh + 8]  = a1;
        *(f16x8*)&B0S[ar][akh]     = *(const f16x8*)(pB0 + k0);
        *(f16x8*)&B0S[ar][akh + 8] = *(const f16x8*)(pB0 + k0 + 8);
        *(f16x8*)&B1S[ar][akh]     = *(const f16x8*)(pB1 + k0);
        *(f16x8*)&B1S[ar][akh + 8] = *(const f16x8*)(pB1 + k0 + 8);
        __syncthreads();

        f16x8 fA[4];
#pragma unroll
        for (int fi = 0; fi < 4; fi++) {
            int r = wr * 64 + fi * 16 + rr;
            fA[fi] = *(const f16x8*)&AS[r][quad * 8];
        }
#pragma unroll
        for (int fj = 0; fj < 4; fj++) {
            int c = wc * 64 + fj * 16 + rr;
            f16x8 b0 = *(const f16x8*)&B0S[c][quad * 8];
            f16x8 b1 = *(const f16x8*)&B1S[c][quad * 8];
#pragma unroll
            for (int fi = 0; fi < 4; fi++) {
                acc0[fi][fj] = __builtin_amdgcn_mfma_f32_16x16x32_f16(fA[fi], b0, acc0[fi][fj], 0, 0, 0);
                acc1[fi][fj] = __builtin_amdgcn_mfma_f32_16x16x32_f16(fA[fi], b1, acc1[fi][fj], 0, 0, 0);
            }
        }
        __syncthreads();
    }

#pragma unroll
    for (int fj = 0; fj < 4; fj++) {
        int gc = col0 + wc * 64 + fj * 16 + rr;
        if (gc >= N) continue;
        float bb0 = bias0 ? bias0[gc] : 0.f;
        float bb1 = bias1 ? bias1[gc] : 0.f;
#pragma unroll
        for (int fi = 0; fi < 4; fi++) {
#pragma unroll
            for (int r = 0; r < 4; r++) {
                int grr = row0 + wr * 64 + fi * 16 + quad * 4 + r;
                if (grr < M) {
                    float v0 = acc0[fi][fj][r] + bb0;
                    float v1 = acc1[fi][fj][r] + bb1;
                    if (fmt & 1) ((u16*)C0v)[(size_t)grr * 256 + gc] = f2h(v0);
                    else         ((float*)C0v)[(size_t)grr * N + gc] = v0;
                    if (fmt & 2) ((u16*)C1v)[(size_t)grr * 256 + gc] = f2h(v1);
                    else         ((float*)C1v)[(size_t)grr * N + gc] = v1;
                }
            }
        }
    }
}

// ---------------- fused edge phase: packed-fp16 single-pass softmax+aggregate ----------------
// 4-edge unroll full-wave; wave-uniform scalarized offsets; xl/xr fp16 stride-256.
// Butterfly reduction packed as two fp16 pairs (e0,e1)/(e2,e3): 12 shfl + 12 pk_add
// instead of 24 shfl + 24 add (partials are fp32 from fdot2; 6 fp16 adds add ~1e-3
// abs error on scores, below the accepted fp16 input quantization).

__global__ __launch_bounds__(256) void fused_edge_kernel(
    const int* __restrict__ rowptr, const int* __restrict__ ssrc,
    const u16* __restrict__ xl16, const u16* __restrict__ xr16,
    const float* __restrict__ att,
    u16* __restrict__ Oh, int dorelu)
{
    int i = blockIdx.x * 4 + (threadIdx.x >> 6);
    if (i >= NN) return;
    int lane = threadIdx.x & 63;
    int beg = __builtin_amdgcn_readfirstlane(rowptr[i]);
    int end = __builtin_amdgcn_readfirstlane(rowptr[i + 1]);
    int d0 = lane * 4;
    int lb = d0 * 2;                 // lane byte offset into fp16 row

    // xr chunk: direct fp16 load (pads garbage but killed by zero att)
    uint2 xrr = *(const uint2*)&xr16[(size_t)i * 256 + d0];
    h2v xr0h = *(h2v*)&xrr.x, xr1h = *(h2v*)&xrr.y;
    // att: masked fp32 loads -> fp16 (pads exact zero)
    float atf[4] = {0.f, 0.f, 0.f, 0.f};
#pragma unroll
    for (int j = 0; j < 4; j++)
        if (d0 + j < DD) atf[j] = att[d0 + j];
    h2v at0h, at1h;
    at0h.x = (_Float16)atf[0]; at0h.y = (_Float16)atf[1];
    at1h.x = (_Float16)atf[2]; at1h.y = (_Float16)atf[3];
    const h2v c02 = {(_Float16)0.2f, (_Float16)0.2f};

    const char* xlb = (const char*)xl16;

    float m = -1e30f, ssum = 0.f;
    float4 acc = make_float4(0.f, 0.f, 0.f, 0.f);

    int p = beg;
    for (; p + 3 < end; p += 4) {
        int o0 = __builtin_amdgcn_readfirstlane(ssrc[p]);
        int o1 = __builtin_amdgcn_readfirstlane(ssrc[p + 1]);
        int o2 = __builtin_amdgcn_readfirstlane(ssrc[p + 2]);
        int o3 = __builtin_amdgcn_readfirstlane(ssrc[p + 3]);
        uint2 r0 = *(const uint2*)(xlb + o0 + lb);
        uint2 r1 = *(const uint2*)(xlb + o1 + lb);
        uint2 r2 = *(const uint2*)(xlb + o2 + lb);
        uint2 r3 = *(const uint2*)(xlb + o3 + lb);
        h2v x00 = *(h2v*)&r0.x, x01 = *(h2v*)&r0.y;
        h2v x10 = *(h2v*)&r1.x, x11 = *(h2v*)&r1.y;
        h2v x20 = *(h2v*)&r2.x, x21 = *(h2v*)&r2.y;
        h2v x30 = *(h2v*)&r3.x, x31 = *(h2v*)&r3.y;

        h2v s;
        float e0, e1, e2, e3;
        s = x00 + xr0h; s = hmax2v(s, s * c02);
        e0 = __builtin_amdgcn_fdot2(s, at0h, 0.f, false);
        s = x01 + xr1h; s = hmax2v(s, s * c02);
        e0 = __builtin_amdgcn_fdot2(s, at1h, e0, false);
        s = x10 + xr0h; s = hmax2v(s, s * c02);
        e1 = __builtin_amdgcn_fdot2(s, at0h, 0.f, false);
        s = x11 + xr1h; s = hmax2v(s, s * c02);
        e1 = __builtin_amdgcn_fdot2(s, at1h, e1, false);
        s = x20 + xr0h; s = hmax2v(s, s * c02);
        e2 = __builtin_amdgcn_fdot2(s, at0h, 0.f, false);
        s = x21 + xr1h; s = hmax2v(s, s * c02);
        e2 = __builtin_amdgcn_fdot2(s, at1h, e2, false);
        s = x30 + xr0h; s = hmax2v(s, s * c02);
        e3 = __builtin_amdgcn_fdot2(s, at0h, 0.f, false);
        s = x31 + xr1h; s = hmax2v(s, s * c02);
        e3 = __builtin_amdgcn_fdot2(s, at1h, e3, false);

        // packed-pair butterfly: two fp16 pairs reduced simultaneously
        H2U u01, u23;
        u01.h.x = (_Float16)e0; u01.h.y = (_Float16)e1;
        u23.h.x = (_Float16)e2; u23.h.y = (_Float16)e3;
#pragma unroll
        for (int off = 1; off < 64; off <<= 1) {
            H2U t01, t23;
            t01.u = (unsigned int)__shfl_xor((int)u01.u, off, 64);
            t23.u = (unsigned int)__shfl_xor((int)u23.u, off, 64);
            u01.h = u01.h + t01.h;
            u23.h = u23.h + t23.h;
        }
        float es0 = (float)u01.h.x, es1 = (float)u01.h.y;
        float es2 = (float)u23.h.x, es3 = (float)u23.h.y;

        float nm = fmaxf(fmaxf(m, es0), fmaxf(fmaxf(es1, es2), es3));
        float sc = __expf(m - nm);
        float w0 = __expf(es0 - nm);
        float w1 = __expf(es1 - nm);
        float w2 = __expf(es2 - nm);
        float w3 = __expf(es3 - nm);
        // tree-paired accumulate (short dep chains; fma_mix folds the h->f cvt)
        float ax0 = fmaf(w1, (float)x10.x, w0 * (float)x00.x);
        float ax1 = fmaf(w3, (float)x30.x, w2 * (float)x20.x);
        float ay0 = fmaf(w1, (float)x10.y, w0 * (float)x00.y);
        float ay1 = fmaf(w3, (float)x30.y, w2 * (float)x20.y);
        float az0 = fmaf(w1, (float)x11.x, w0 * (float)x01.x);
        float az1 = fmaf(w3, (float)x31.x, w2 * (float)x21.x);
        float aw0 = fmaf(w1, (float)x11.y, w0 * (float)x01.y);
        float aw1 = fmaf(w3, (float)x31.y, w2 * (float)x21.y);
        acc.x = fmaf(acc.x, sc, ax0 + ax1);
        acc.y = fmaf(acc.y, sc, ay0 + ay1);
        acc.z = fmaf(acc.z, sc, az0 + az1);
        acc.w = fmaf(acc.w, sc, aw0 + aw1);
        ssum = fmaf(ssum, sc, (w0 + w1) + (w2 + w3));
        m = nm;
    }
    for (; p < end; p++) {
        int o = __builtin_amdgcn_readfirstlane(ssrc[p]);
        uint2 r = *(const uint2*)(xlb + o + lb);
        h2v x0 = *(h2v*)&r.x, x1 = *(h2v*)&r.y;
        h2v s;
        float e;
        s = x0 + xr0h; s = hmax2v(s, s * c02);
        e = __builtin_amdgcn_fdot2(s, at0h, 0.f, false);
        s = x1 + xr1h; s = hmax2v(s, s * c02);
        e = __builtin_amdgcn_fdot2(s, at1h, e, false);
#pragma unroll
        for (int off = 1; off < 64; off <<= 1)
            e += __shfl_xor(e, off, 64);
        float nm = fmaxf(m, e);
        float sc = __expf(m - nm);
        float w = __expf(e - nm);
        acc.x = fmaf(w, (float)x0.x, acc.x * sc);
        acc.y = fmaf(w, (float)x0.y, acc.y * sc);
        acc.z = fmaf(w, (float)x1.x, acc.z * sc);
        acc.w = fmaf(w, (float)x1.y, acc.w * sc);
        ssum = fmaf(ssum, sc, w);
        m = nm;
    }

    float inv = 1.f / ssum;
    acc.x *= inv; acc.y *= inv; acc.z *= inv; acc.w *= inv;
    if (dorelu) {
        acc.x = fmaxf(acc.x, 0.f); acc.y = fmaxf(acc.y, 0.f);
        acc.z = fmaxf(acc.z, 0.f); acc.w = fmaxf(acc.w, 0.f);
    }
    size_t base = (size_t)i * 256 + d0;
    ushort4 hv;
    hv.x = f2h(acc.x); hv.y = f2h(acc.y); hv.z = f2h(acc.z); hv.w = f2h(acc.w);
    *(ushort4*)&Oh[base] = hv;   // pad lanes write their (harmless) values; B k-pads are zero
}

// ---------------- query head: 2 queries per wave; fp16 gathers; uniform indices ----------------

__global__ __launch_bounds__(256) void query_kernel(
    const int* __restrict__ qry, const u16* __restrict__ Ptop,
    const u16* __restrict__ Pbot, const float* __restrict__ Wm2,
    const float* __restrict__ bm2, float* __restrict__ out)
{
    int q = (blockIdx.x * 4 + (threadIdx.x >> 6)) * 2;
    if (q >= NQ) return;
    int lane = threadIdx.x & 63;
    int a0 = __builtin_amdgcn_readfirstlane(qry[q * 2 + 0]);
    int b0 = __builtin_amdgcn_readfirstlane(qry[q * 2 + 1]);
    int a1 = __builtin_amdgcn_readfirstlane(qry[q * 2 + 2]);
    int b1 = __builtin_amdgcn_readfirstlane(qry[q * 2 + 3]);
    float4 w  = *(const float4*)&Wm2[lane * 4];
    float4 t0 = ld4h(&Ptop[(size_t)a0 * HD + lane * 4]);
    float4 v0 = ld4h(&Pbot[(size_t)b0 * HD + lane * 4]);
    float4 t1 = ld4h(&Ptop[(size_t)a1 * HD + lane * 4]);
    float4 v1 = ld4h(&Pbot[(size_t)b1 * HD + lane * 4]);
    float s0 = fmaxf(t0.x + v0.x, 0.f) * w.x + fmaxf(t0.y + v0.y, 0.f) * w.y
             + fmaxf(t0.z + v0.z, 0.f) * w.z + fmaxf(t0.w + v0.w, 0.f) * w.w;
    float s1 = fmaxf(t1.x + v1.x, 0.f) * w.x + fmaxf(t1.y + v1.y, 0.f) * w.y
             + fmaxf(t1.z + v1.z, 0.f) * w.z + fmaxf(t1.w + v1.w, 0.f) * w.w;
#pragma unroll
    for (int off = 32; off > 0; off >>= 1) {
        s0 += __shfl_down(s0, off, 64);
        s1 += __shfl_down(s1, off, 64);
    }
    if (lane == 0) {
        float bb = bm2[0];
        out[q] = fmaxf(s0 + bb, 0.f);
        if (q + 1 < NQ) out[q + 1] = fmaxf(s1 + bb, 0.f);
    }
}

// ---------------- launch ----------------

extern "C" void kernel_launch(void* const* d_in, const int* in_sizes, int n_in,
                              void* d_out, int out_size, void* d_ws, size_t ws_size,
                              hipStream_t stream) {
    const float* x    = (const float*)d_in[0];
    const int*   ei   = (const int*)d_in[1];
    const int*   qry  = (const int*)d_in[2];
    const float* W1l  = (const float*)d_in[3];
    const float* b1l  = (const float*)d_in[4];
    const float* W1r  = (const float*)d_in[5];
    const float* b1r  = (const float*)d_in[6];
    const float* att1 = (const float*)d_in[7];
    const float* W2l  = (const float*)d_in[8];
    const float* b2l  = (const float*)d_in[9];
    const float* W2r  = (const float*)d_in[10];
    const float* b2r  = (const float*)d_in[11];
    const float* att2 = (const float*)d_in[12];
    const float* Wm1  = (const float*)d_in[13];
    const float* bm1  = (const float*)d_in[14];
    const float* Wm2  = (const float*)d_in[15];
    const float* bm2  = (const float*)d_in[16];
    float* out = (float*)d_out;

    // workspace carve-up (all node tensors fp16 stride-256 now)
    u16* xl16    = (u16*)d_ws;                   // NN*256 halfs (25.6 MB)
    u16* xr16    = xl16 + (size_t)NN * 256;      // NN*256 halfs (25.6 MB)
    int* rowptr  = (int*)(xr16 + (size_t)NN * 256);  // NN+1
    int* fill    = rowptr + NN + 1;              // NN (count buffer)
    int* ssrc    = fill + NN;                    // ET
    int* bsum    = ssrc + ET;                    // 256
    uintptr_t wp = (uintptr_t)(bsum + 256);
    wp = (wp + 63) & ~(uintptr_t)63;
    u16* W1lT = (u16*)wp;                        // 256*128 each
    u16* W1rT = W1lT + 256 * 128;
    u16* W2lT = W1rT + 256 * 128;                // 256*256 each from here
    u16* W2rT = W2lT + 65536;
    u16* WmtT = W2rT + 65536;
    u16* WmbT = WmtT + 65536;
    u16* Asp  = WmbT + 65536;                    // NN*256 fp16 (x [NN][128] early, then h/emb [NN][256])
    // head fp16 buffers overlay xl16 / xr16 (both dead after layer-2 fused_edge)
    u16* Ptop16 = xl16;                          // NN*256 halfs
    u16* Pbot16 = xr16;                          // NN*256 halfs

    dim3 blk(256);
    int gET = (ET + 255) / 256;
    int gNode = (NN + 3) / 4;
    int nb = (NN + 255) / 256;                   // 196 scan blocks
    dim3 gg((NN + 127) / 128, 2);

    // ---- conversions + fill zeroing (one dispatch) ----
    conv_all<<<CONVX_BLOCKS + 1280, blk, 0, stream>>>(x, fill, Asp,
        W1l, W1r, W2l, W2r, Wm1,
        W1lT, W1rT, W2lT, W2rT, WmtT, WmbT);

    // ---- CSR build ----
    count_kernel<<<gET, blk, 0, stream>>>(ei, fill);
    scan1_kernel<<<nb, blk, 0, stream>>>(fill, rowptr, bsum);   // also zeroes fill
    scan2_kernel<<<1, blk, 0, stream>>>(bsum, rowptr, nb);
    scan3_kernel<<<nb, blk, 0, stream>>>(rowptr, bsum);
    scatter_kernel<<<gET, blk, 0, stream>>>(ei, rowptr, fill, ssrc);

    // ---- layer 1 (A = x fp16, Kp=128): both outputs fp16 stride-256 ----
    gemm_pair<<<gg, blk, 0, stream>>>(Asp, 128, W1lT, W1rT,
                                      b1l, b1r, (void*)xl16, (void*)xr16, NN, DD, 3);
    fused_edge_kernel<<<gNode, blk, 0, stream>>>(rowptr, ssrc, xl16, xr16, att1, Asp, 1);

    // ---- layer 2 (A = h fp16, Kp=256) ----
    gemm_pair<<<gg, blk, 0, stream>>>(Asp, 256, W2lT, W2rT,
                                      b2l, b2r, (void*)xl16, (void*)xr16, NN, DD, 3);
    fused_edge_kernel<<<gNode, blk, 0, stream>>>(rowptr, ssrc, xl16, xr16, att2, Asp, 0);

    // ---- head precompute (A = emb fp16, Kp=256): both outputs fp16 ----
    gemm_pair<<<gg, blk, 0, stream>>>(Asp, 256, WmtT, WmbT,
                                      bm1, (const float*)nullptr, (void*)Ptop16, (void*)Pbot16, NN, HD, 3);

    // ---- per-query head ----
    query_kernel<<<(NQ / 2 + 3) / 4, blk, 0, stream>>>(qry, Ptop16, Pbot16, Wm2, bm2, out);
}